// Round 1
// baseline (449.646 us; speedup 1.0000x reference)
//
#include <hip/hip_runtime.h>

#define N_NODES   100000
#define N_EDGES   1600000
#define NFEAT     128
#define N_GRAPHS  1024

// ---- bucketed CSR build ----
#define BSHIFT  8
#define BNODES  256
#define NBUCK   391                  // ceil(100000 / 256)
#define BCAP    4608                 // mean 4096 + 8 sigma
#define SC_EDGES 4096
#define SC_EPT   8                   // edges per thread (4096/512)
#define SC_BLOCKS 391                // ceil(1.6M / 4096)
#define BD_EPT   18                  // ceil(BCAP/256)

#define WT_STRIDE 136
#define GEMM_BLOCKS 782              // ceil(100000/128)

typedef unsigned int uint32;
typedef unsigned short ushort;
typedef __attribute__((ext_vector_type(8))) short short8;   // 8 bf16 (4 VGPRs)
typedef __attribute__((ext_vector_type(4))) float f32x4;

// fp32 -> bf16 bits, round-to-nearest-even (finite inputs)
__device__ inline ushort f2b(float f) {
    uint32 x = __float_as_uint(f);
    uint32 r = x + 0x7fffu + ((x >> 16) & 1u);
    return (ushort)(r >> 16);
}
__device__ inline float blo(uint32 u) { return __uint_as_float(u << 16); }
__device__ inline float bhi(uint32 u) { return __uint_as_float(u & 0xffff0000u); }

__device__ inline short8 cvt8(const float* p) {
    float4 v0 = ((const float4*)p)[0];
    float4 v1 = ((const float4*)p)[1];
    short8 r;
    r[0] = (short)f2b(v0.x); r[1] = (short)f2b(v0.y);
    r[2] = (short)f2b(v0.z); r[3] = (short)f2b(v0.w);
    r[4] = (short)f2b(v1.x); r[5] = (short)f2b(v1.y);
    r[6] = (short)f2b(v1.z); r[7] = (short)f2b(v1.w);
    return r;
}

// ---------------- cast+transpose W -> WT bf16 [layer][n][k]; also zero cur ----------------
__global__ __launch_bounds__(256) void k_castw(const float* __restrict__ W1, const float* __restrict__ W2,
                                               const float* __restrict__ W3, ushort* __restrict__ WT,
                                               int* __restrict__ cur) {
    int i = blockIdx.x * blockDim.x + threadIdx.x;   // 3*16384
    if (i < NBUCK) cur[i] = 0;
    if (i >= 3 * NFEAT * NFEAT) return;
    int l = i >> 14;
    int j = i & 16383;
    int n = j >> 7;
    int k = j & 127;
    const float* W = (l == 0) ? W1 : (l == 1) ? W2 : W3;
    WT[i] = f2b(W[k * NFEAT + n]);   // WT[l][n*128+k] = W[k][n]
}

// ---------------- phase 1: scatter (blocks 0..390) || layer-1 GEMM (blocks 391..1172) ----------------
struct SMemScatter {
    int hist[NBUCK], lofs[NBUCK], gbase[NBUCK];
    int wsum[4];
    uint32 sortedP[SC_EDGES];   // 16 KB
    ushort sortedB[SC_EDGES];   //  8 KB
};

__global__ __launch_bounds__(512) void k_phase1(const int* __restrict__ src, const int* __restrict__ dst,
                                                int* __restrict__ cur, uint32* __restrict__ bbuf,
                                                const float* __restrict__ A, const ushort* __restrict__ WTl,
                                                ushort* __restrict__ C, int M) {
    __shared__ __align__(16) char smem[NFEAT * WT_STRIDE * 2];   // 34 KB >= sizeof(SMemScatter)
    int t = threadIdx.x;
    if (blockIdx.x < SC_BLOCKS) {
        // ================== scatter: single-pass ticketed counting sort ==================
        SMemScatter& S = *(SMemScatter*)smem;
        int e0 = blockIdx.x * SC_EDGES;
        int total = N_EDGES - e0; if (total > SC_EDGES) total = SC_EDGES; if (total < 0) total = 0;
        for (int i = t; i < NBUCK; i += 512) S.hist[i] = 0;
        __syncthreads();
        uint32 val[SC_EPT];
        int    meta[SC_EPT];    // (bucket << 13) | ticket
        #pragma unroll
        for (int k = 0; k < SC_EPT; ++k) {
            int i = t + k * 512;
            meta[k] = -1;
            if (i < total) {
                int s = src[e0 + i], d = dst[e0 + i];
                int b = d >> BSHIFT;
                int tk = atomicAdd(&S.hist[b], 1);
                val[k] = ((uint32)(d & (BNODES - 1)) << 17) | (uint32)s;
                meta[k] = (b << 13) | tk;
            }
        }
        __syncthreads();
        // scan of 391 bins on first 256 threads (2/thread) + per-bin global reservation
        int inc = 0, ts = 0, h0 = 0;
        if (t < 256) {
            int b0 = 2 * t, b1 = 2 * t + 1;
            h0 = (b0 < NBUCK) ? S.hist[b0] : 0;
            int h1 = (b1 < NBUCK) ? S.hist[b1] : 0;
            ts = h0 + h1;
            int lane = t & 63;
            inc = ts;
            #pragma unroll
            for (int d = 1; d < 64; d <<= 1) {
                int u = __shfl_up(inc, d, 64);
                if (lane >= d) inc += u;
            }
            if (lane == 63) S.wsum[t >> 6] = inc;
        }
        __syncthreads();
        if (t < 256) {
            int w = t >> 6;
            int wpre = 0;
            for (int i = 0; i < w; ++i) wpre += S.wsum[i];
            int run = wpre + inc - ts;
            int b0 = 2 * t, b1 = 2 * t + 1;
            int h1 = ts - h0;
            if (b0 < NBUCK) {
                S.lofs[b0] = run;
                if (h0) S.gbase[b0] = atomicAdd(&cur[b0], h0);
            }
            if (b1 < NBUCK) {
                S.lofs[b1] = run + h0;
                if (h1) S.gbase[b1] = atomicAdd(&cur[b1], h1);
            }
        }
        __syncthreads();
        #pragma unroll
        for (int k = 0; k < SC_EPT; ++k) {
            if (meta[k] >= 0) {
                int b = meta[k] >> 13;
                int p = S.lofs[b] + (meta[k] & 0x1FFF);
                S.sortedP[p] = val[k];
                S.sortedB[p] = (ushort)b;
            }
        }
        __syncthreads();
        for (int i = t; i < total; i += 512) {
            int b = S.sortedB[i];
            int addr = S.gbase[b] + (i - S.lofs[b]);
            if (addr < BCAP)
                bbuf[(size_t)b * BCAP + addr] = S.sortedP[i];
        }
    } else {
        // ================== layer-1 GEMM (fp32 A, cast fused) ==================
        ushort* sWT = (ushort*)smem;
        int gb = blockIdx.x - SC_BLOCKS;
        for (int i = t; i < NFEAT * 16; i += 512) {
            int n = i >> 4, c = i & 15;
            *(float4*)(sWT + n * WT_STRIDE + c * 8) = ((const float4*)WTl)[i];
        }
        int wave = t >> 6, lane = t & 63;
        int m0 = gb * 128 + wave * 16;
        int mRow = m0 + (lane & 15);
        if (mRow >= M) mRow = M - 1;
        int kg = lane >> 4;
        const float* Ap = A + (size_t)mRow * NFEAT + kg * 8;
        short8 a0 = cvt8(Ap);
        short8 a1 = cvt8(Ap + 32);
        short8 a2 = cvt8(Ap + 64);
        short8 a3 = cvt8(Ap + 96);
        __syncthreads();

        f32x4 acc[8];
        #pragma unroll
        for (int nt = 0; nt < 8; ++nt) acc[nt] = (f32x4){0.f, 0.f, 0.f, 0.f};
        #pragma unroll
        for (int nt = 0; nt < 8; ++nt) {
            int n = nt * 16 + (lane & 15);
            const short8* Bp = (const short8*)(sWT + n * WT_STRIDE + kg * 8);
            short8 b0 = Bp[0];
            short8 b1 = Bp[4];
            short8 b2 = Bp[8];
            short8 b3 = Bp[12];
            acc[nt] = __builtin_amdgcn_mfma_f32_16x16x32_bf16(a0, b0, acc[nt], 0, 0, 0);
            acc[nt] = __builtin_amdgcn_mfma_f32_16x16x32_bf16(a1, b1, acc[nt], 0, 0, 0);
            acc[nt] = __builtin_amdgcn_mfma_f32_16x16x32_bf16(a2, b2, acc[nt], 0, 0, 0);
            acc[nt] = __builtin_amdgcn_mfma_f32_16x16x32_bf16(a3, b3, acc[nt], 0, 0, 0);
        }
        __syncthreads();
        {
            int colBase = lane & 15;
            #pragma unroll
            for (int r = 0; r < 4; ++r) {
                int lr = wave * 16 + kg * 4 + r;
                #pragma unroll
                for (int nt = 0; nt < 8; ++nt)
                    sWT[lr * NFEAT + nt * 16 + colBase] = f2b(acc[nt][r]);
            }
        }
        __syncthreads();
        {
            int rowBase = gb * 128;
            const float4* sC4 = (const float4*)sWT;
            for (int i = t; i < 2048; i += 512) {
                int row = i >> 4;
                int gr = rowBase + row;
                if (gr < M) ((float4*)(C + (size_t)gr * NFEAT))[i & 15] = sC4[i];
            }
        }
    }
}

// ---------------- per-bucket ticketed counting sort -> CSR col + offsets + dinv ----------------
__global__ __launch_bounds__(256) void k_build(const uint32* __restrict__ bbuf, const int* __restrict__ cur,
                                               int* __restrict__ col, int* __restrict__ offsets,
                                               float* __restrict__ dinv) {
    int b = blockIdx.x;
    __shared__ int hist[BNODES], excl[BNODES];
    __shared__ int wsum[4], wtot[4];
    __shared__ int sorted[BCAP];              // 18 KB
    __shared__ int sBase, sTotal;
    int t = threadIdx.x;
    {
        int pre = 0, tot = 0;
        #pragma unroll
        for (int q = 0; q < 2; ++q) {
            int i = 2 * t + q;
            if (i < NBUCK) {
                int v = cur[i]; if (v > BCAP) v = BCAP;
                tot += v;
                if (i < b) pre += v;
            }
        }
        int lane = t & 63, w = t >> 6;
        #pragma unroll
        for (int d = 32; d > 0; d >>= 1) { pre += __shfl_down(pre, d, 64); tot += __shfl_down(tot, d, 64); }
        if (lane == 0) { wsum[w] = pre; wtot[w] = tot; }
        __syncthreads();
        if (t == 0) {
            sBase = wsum[0] + wsum[1] + wsum[2] + wsum[3];
            sTotal = wtot[0] + wtot[1] + wtot[2] + wtot[3];
        }
        hist[t] = 0;
    }
    __syncthreads();
    int base = sBase;
    if (b == NBUCK - 1 && t == 0) offsets[N_NODES] = sTotal;
    int cnt = cur[b]; if (cnt > BCAP) cnt = BCAP;
    const uint32* reg = bbuf + (size_t)b * BCAP;

    uint32 val[BD_EPT];
    int    meta[BD_EPT];   // (node << 16) | ticket
    #pragma unroll
    for (int k = 0; k < BD_EPT; ++k) {
        int i = t + k * 256;
        meta[k] = -1;
        if (i < cnt) {
            uint32 p = reg[i];
            int node = p >> 17;
            int tk = atomicAdd(&hist[node], 1);
            val[k] = p & 0x1FFFF;
            meta[k] = (node << 16) | tk;
        }
    }
    __syncthreads();
    {
        int c = hist[t];
        int lane = t & 63, w = t >> 6;
        int inc = c;
        #pragma unroll
        for (int d = 1; d < 64; d <<= 1) {
            int u = __shfl_up(inc, d, 64);
            if (lane >= d) inc += u;
        }
        if (lane == 63) wsum[w] = inc;
        __syncthreads();
        int wpre = 0;
        for (int i = 0; i < w; ++i) wpre += wsum[i];
        int e = wpre + inc - c;
        excl[t] = e;
        int node = (b << BSHIFT) + t;
        if (node < N_NODES) {
            offsets[node] = base + e;
            dinv[node] = rsqrtf((float)(c + 1));
        }
    }
    __syncthreads();
    #pragma unroll
    for (int k = 0; k < BD_EPT; ++k) {
        if (meta[k] >= 0) {
            int node = meta[k] >> 16;
            sorted[excl[node] + (meta[k] & 0xFFFF)] = (int)val[k];
        }
    }
    __syncthreads();
    for (int i = t; i < cnt; i += 256) col[base + i] = sorted[i];
}

// ---------------- aggregation core: 4 edges per uint4 gather instruction ----------------
#define AGG_BODY4 \
    float dn = dinv[n]; \
    int half = lane >> 4; \
    int fl = lane & 15; \
    const uint4* XW4 = (const uint4*)XWu; \
    uint4 sv = XW4[(size_t)n * 16 + fl]; \
    float ws = (half == 0) ? dn * dn : 0.f; \
    float a0 = ws * blo(sv.x), a1 = ws * bhi(sv.x); \
    float a2 = ws * blo(sv.y), a3 = ws * bhi(sv.y); \
    float a4 = ws * blo(sv.z), a5 = ws * bhi(sv.z); \
    float a6 = ws * blo(sv.w), a7 = ws * bhi(sv.w); \
    int e0 = off[n], e1 = off[n + 1]; \
    for (int base = e0; base < e1; base += 64) { \
        int len = e1 - base; if (len > 64) len = 64; \
        int cm = (lane < len) ? col[base + lane] : 0; \
        float wm = (lane < len) ? dn * dinv[cm] : 0.f; \
        int j = 0; \
        for (; j + 16 <= len; j += 16) { \
            uint4 u[4]; float w[4]; \
            _Pragma("unroll") \
            for (int p = 0; p < 4; ++p) { \
                int idx = j + 4 * p + half; \
                int cc = __shfl(cm, idx, 64); \
                w[p] = __shfl(wm, idx, 64); \
                u[p] = XW4[(size_t)cc * 16 + fl]; \
            } \
            _Pragma("unroll") \
            for (int p = 0; p < 4; ++p) { \
                a0 = fmaf(w[p], blo(u[p].x), a0); a1 = fmaf(w[p], bhi(u[p].x), a1); \
                a2 = fmaf(w[p], blo(u[p].y), a2); a3 = fmaf(w[p], bhi(u[p].y), a3); \
                a4 = fmaf(w[p], blo(u[p].z), a4); a5 = fmaf(w[p], bhi(u[p].z), a5); \
                a6 = fmaf(w[p], blo(u[p].w), a6); a7 = fmaf(w[p], bhi(u[p].w), a7); \
            } \
        } \
        for (; j < len; j += 4) { \
            int rem = len - j; \
            int idx = j + ((half < rem) ? half : 0); \
            int cc = __shfl(cm, idx, 64); \
            float ww = __shfl(wm, idx, 64); \
            if (half >= rem) ww = 0.f; \
            uint4 u = XW4[(size_t)cc * 16 + fl]; \
            a0 = fmaf(ww, blo(u.x), a0); a1 = fmaf(ww, bhi(u.x), a1); \
            a2 = fmaf(ww, blo(u.y), a2); a3 = fmaf(ww, bhi(u.y), a3); \
            a4 = fmaf(ww, blo(u.z), a4); a5 = fmaf(ww, bhi(u.z), a5); \
            a6 = fmaf(ww, blo(u.w), a6); a7 = fmaf(ww, bhi(u.w), a7); \
        } \
    } \
    a0 += __shfl_xor(a0, 32, 64); a0 += __shfl_xor(a0, 16, 64); \
    a1 += __shfl_xor(a1, 32, 64); a1 += __shfl_xor(a1, 16, 64); \
    a2 += __shfl_xor(a2, 32, 64); a2 += __shfl_xor(a2, 16, 64); \
    a3 += __shfl_xor(a3, 32, 64); a3 += __shfl_xor(a3, 16, 64); \
    a4 += __shfl_xor(a4, 32, 64); a4 += __shfl_xor(a4, 16, 64); \
    a5 += __shfl_xor(a5, 32, 64); a5 += __shfl_xor(a5, 16, 64); \
    a6 += __shfl_xor(a6, 32, 64); a6 += __shfl_xor(a6, 16, 64); \
    a7 += __shfl_xor(a7, 32, 64); a7 += __shfl_xor(a7, 16, 64);

// ---------------- fused: aggregate(+bias,relu) 128 nodes -> LDS tile -> MFMA @ W_next ----------------
// Eliminates the H round-trip through HBM (write 25.6MB + read 25.6MB per layer).
// B-fragments read straight from global WT (32 KB, L1/L2-hot); LDS holds only the A-tile.
__global__ __launch_bounds__(512) void k_agg_gemm(const uint32* __restrict__ XWu,
                                                  const int* __restrict__ col,
                                                  const int* __restrict__ off,
                                                  const float* __restrict__ dinv,
                                                  const float* __restrict__ bias,
                                                  const ushort* __restrict__ WTl,
                                                  ushort* __restrict__ C, int M) {
    __shared__ __align__(16) ushort sA[NFEAT * WT_STRIDE];   // 34 KB: agg-output A-tile, reused for C staging
    int t = threadIdx.x;
    int wave = t >> 6, lane = t & 63;
    int flh = lane & 15;
    float4 bb0 = ((const float4*)bias)[2 * flh];
    float4 bb1 = ((const float4*)bias)[2 * flh + 1];
    int rowBase = blockIdx.x * 128;
    // ---- phase A: each of 8 waves aggregates 16 nodes, writes relu(agg+b) rows as bf16 ----
    for (int i = 0; i < 16; ++i) {
        int lr = wave * 16 + i;
        int n = rowBase + lr;
        if (n >= M) n = M - 1;   // tail rows duplicate node M-1; final store is guarded
        AGG_BODY4
        if (half == 0) {
            float r0 = fmaxf(a0 + bb0.x, 0.f), r1 = fmaxf(a1 + bb0.y, 0.f);
            float r2 = fmaxf(a2 + bb0.z, 0.f), r3 = fmaxf(a3 + bb0.w, 0.f);
            float r4 = fmaxf(a4 + bb1.x, 0.f), r5 = fmaxf(a5 + bb1.y, 0.f);
            float r6 = fmaxf(a6 + bb1.z, 0.f), r7 = fmaxf(a7 + bb1.w, 0.f);
            uint4 o;
            o.x = (uint32)f2b(r0) | ((uint32)f2b(r1) << 16);
            o.y = (uint32)f2b(r2) | ((uint32)f2b(r3) << 16);
            o.z = (uint32)f2b(r4) | ((uint32)f2b(r5) << 16);
            o.w = (uint32)f2b(r6) | ((uint32)f2b(r7) << 16);
            *(uint4*)(sA + lr * WT_STRIDE + fl * 8) = o;
        }
    }
    __syncthreads();
    // ---- phase B: C_tile[128,128] = sA @ W  (identical fragment scheme to verified k_gemm) ----
    int kg = lane >> 4;
    int rloc = wave * 16 + (lane & 15);
    const short8* Ap = (const short8*)(sA + rloc * WT_STRIDE + kg * 8);
    short8 a0 = Ap[0];
    short8 a1 = Ap[4];
    short8 a2 = Ap[8];
    short8 a3 = Ap[12];
    f32x4 acc[8];
    #pragma unroll
    for (int nt = 0; nt < 8; ++nt) acc[nt] = (f32x4){0.f, 0.f, 0.f, 0.f};
    #pragma unroll
    for (int nt = 0; nt < 8; ++nt) {
        int n = nt * 16 + (lane & 15);
        const short8* Bp = (const short8*)(WTl + n * NFEAT + kg * 8);
        short8 b0 = Bp[0];
        short8 b1 = Bp[4];
        short8 b2 = Bp[8];
        short8 b3 = Bp[12];
        acc[nt] = __builtin_amdgcn_mfma_f32_16x16x32_bf16(a0, b0, acc[nt], 0, 0, 0);
        acc[nt] = __builtin_amdgcn_mfma_f32_16x16x32_bf16(a1, b1, acc[nt], 0, 0, 0);
        acc[nt] = __builtin_amdgcn_mfma_f32_16x16x32_bf16(a2, b2, acc[nt], 0, 0, 0);
        acc[nt] = __builtin_amdgcn_mfma_f32_16x16x32_bf16(a3, b3, acc[nt], 0, 0, 0);
    }
    __syncthreads();
    {
        int colBase = lane & 15;
        #pragma unroll
        for (int r = 0; r < 4; ++r) {
            int lr = wave * 16 + kg * 4 + r;
            #pragma unroll
            for (int nt = 0; nt < 8; ++nt)
                sA[lr * NFEAT + nt * 16 + colBase] = f2b(acc[nt][r]);
        }
    }
    __syncthreads();
    {
        const float4* sC4 = (const float4*)sA;
        for (int i = t; i < 2048; i += 512) {
            int row = i >> 4;
            int gr = rowBase + row;
            if (gr < M) ((float4*)(C + (size_t)gr * NFEAT))[i & 15] = sC4[i];
        }
    }
}

__global__ __launch_bounds__(256) void k_agg_fc(const uint32* __restrict__ XWu, const int* __restrict__ col,
                                                const int* __restrict__ off, const float* __restrict__ dinv,
                                                const float* __restrict__ bias, const float* __restrict__ Wfc,
                                                float* __restrict__ nodeS) {
    int wid = (blockIdx.x * blockDim.x + threadIdx.x) >> 6;
    int lane = threadIdx.x & 63;
    if (wid >= N_NODES) return;
    int n = wid;
    AGG_BODY4
    float4 bb0 = ((const float4*)bias)[2 * fl];
    float4 bb1 = ((const float4*)bias)[2 * fl + 1];
    float4 wf0 = ((const float4*)Wfc)[2 * fl];
    float4 wf1 = ((const float4*)Wfc)[2 * fl + 1];
    float s = fmaxf(a0 + bb0.x, 0.f) * wf0.x + fmaxf(a1 + bb0.y, 0.f) * wf0.y
            + fmaxf(a2 + bb0.z, 0.f) * wf0.z + fmaxf(a3 + bb0.w, 0.f) * wf0.w
            + fmaxf(a4 + bb1.x, 0.f) * wf1.x + fmaxf(a5 + bb1.y, 0.f) * wf1.y
            + fmaxf(a6 + bb1.z, 0.f) * wf1.z + fmaxf(a7 + bb1.w, 0.f) * wf1.w;
    s += __shfl_xor(s, 8, 64);
    s += __shfl_xor(s, 4, 64);
    s += __shfl_xor(s, 2, 64);
    s += __shfl_xor(s, 1, 64);
    if (lane == 0) nodeS[n] = s;
}

// ---------------- segment mean over sorted batch + bias (one block per graph) ----------------
__device__ inline int lower_bound_dev(const int* a, int n, int key) {
    int lo = 0, hi = n;
    while (lo < hi) {
        int mid = (lo + hi) >> 1;
        if (a[mid] < key) lo = mid + 1; else hi = mid;
    }
    return lo;
}

__global__ __launch_bounds__(256) void k_pool(const float* __restrict__ nodeS, const int* __restrict__ batch,
                                              const float* __restrict__ bfc, float* __restrict__ out) {
    int g = blockIdx.x;
    int t = threadIdx.x;
    int lo = lower_bound_dev(batch, N_NODES, g);
    int hi = lower_bound_dev(batch, N_NODES, g + 1);
    float s = 0.f;
    for (int i = lo + t; i < hi; i += 256) s += nodeS[i];
    for (int d = 32; d > 0; d >>= 1) s += __shfl_down(s, d, 64);
    __shared__ float ws[4];
    int lane = t & 63, w = t >> 6;
    if (lane == 0) ws[w] = s;
    __syncthreads();
    if (t == 0) {
        float tot = ws[0] + ws[1] + ws[2] + ws[3];
        float cnt = (float)(hi - lo);
        out[g] = tot / fmaxf(cnt, 1.0f) + bfc[0];
    }
}

// ---------------- launch ----------------
extern "C" void kernel_launch(void* const* d_in, const int* in_sizes, int n_in,
                              void* d_out, int out_size, void* d_ws, size_t ws_size,
                              hipStream_t stream) {
    const float* x    = (const float*)d_in[0];
    const int*   ei   = (const int*)d_in[1];     // [2, E] : row0 = src, row1 = dst
    const int*   batch= (const int*)d_in[2];
    const float* W1   = (const float*)d_in[3];
    const float* b1   = (const float*)d_in[4];
    const float* W2   = (const float*)d_in[5];
    const float* b2   = (const float*)d_in[6];
    const float* W3   = (const float*)d_in[7];
    const float* b3   = (const float*)d_in[8];
    const float* Wfc  = (const float*)d_in[9];
    const float* bfc  = (const float*)d_in[10];
    float* out = (float*)d_out;

    const int* src = ei;
    const int* dst = ei + N_EDGES;

    // carve workspace (256B-aligned)
    char* p = (char*)d_ws;
    auto carve = [&](size_t bytes) { void* r = (void*)p; p += (bytes + 255) & ~(size_t)255; return r; };
    int*    cur       = (int*)   carve(sizeof(int) * NBUCK);
    uint32* bbuf      = (uint32*)carve(sizeof(uint32) * (size_t)NBUCK * BCAP);            // 7.2 MB
    float*  dinv      = (float*) carve(sizeof(float) * N_NODES);
    int*    offsets   = (int*)   carve(sizeof(int) * (N_NODES + 1));
    int*    col       = (int*)   carve(sizeof(int) * N_EDGES);
    ushort* XW        = (ushort*)carve(sizeof(short) * (size_t)N_NODES * NFEAT);
    ushort* XW2       = (ushort*)carve(sizeof(short) * (size_t)N_NODES * NFEAT);          // ping-pong buffer
    ushort* WT        = (ushort*)carve(sizeof(short) * 3 * NFEAT * NFEAT);
    float*  nodeS     = (float*) carve(sizeof(float) * N_NODES);

    const int waveNodeBlocks = (N_NODES * 64 + 255) / 256;   // 25000

    k_castw<<<(3 * NFEAT * NFEAT + 255) / 256, 256, 0, stream>>>(W1, W2, W3, WT, cur);
    // phase 1: scatter || layer-1 GEMM (independent work co-scheduled)  -> XW = x @ W1
    k_phase1<<<SC_BLOCKS + GEMM_BLOCKS, 512, 0, stream>>>(src, dst, cur, bbuf, x, WT, XW, N_NODES);
    k_build<<<NBUCK, 256, 0, stream>>>(bbuf, cur, col, offsets, dinv);

    // fused layer 1 agg + layer 2 GEMM:  XW2 = relu(A·XW + b1) @ W2
    k_agg_gemm<<<GEMM_BLOCKS, 512, 0, stream>>>((const uint32*)XW, col, offsets, dinv, b1,
                                                WT + NFEAT * NFEAT, XW2, N_NODES);
    // fused layer 2 agg + layer 3 GEMM:  XW = relu(A·XW2 + b2) @ W3
    k_agg_gemm<<<GEMM_BLOCKS, 512, 0, stream>>>((const uint32*)XW2, col, offsets, dinv, b2,
                                                WT + 2 * NFEAT * NFEAT, XW, N_NODES);
    // layer 3 agg + FC
    k_agg_fc<<<waveNodeBlocks, 256, 0, stream>>>((const uint32*)XW, col, offsets, dinv, b3, Wfc, nodeS);

    k_pool<<<N_GRAPHS, 256, 0, stream>>>(nodeS, batch, bfc, out);
}

// Round 3
// 357.519 us; speedup vs baseline: 1.2577x; 1.2577x over previous
//
#include <hip/hip_runtime.h>

#define N_NODES   100000
#define N_EDGES   1600000
#define NFEAT     128
#define N_GRAPHS  1024

// ---- bucketed CSR build ----
#define BSHIFT  8
#define BNODES  256
#define NBUCK   391                  // ceil(100000 / 256)
#define BCAP    4608                 // mean 4096 + 8 sigma
#define SC_EDGES 4096
#define SC_EPT   8                   // edges per thread (4096/512)
#define SC_BLOCKS 391                // ceil(1.6M / 4096)
#define BD_EPT   18                  // ceil(BCAP/256)

#define WT_STRIDE 136
#define GEMM_BLOCKS 782              // ceil(100000/128)

typedef unsigned int uint32;
typedef unsigned short ushort;
typedef __attribute__((ext_vector_type(8))) short short8;   // 8 bf16 (4 VGPRs)
typedef __attribute__((ext_vector_type(4))) float f32x4;

// fp32 -> bf16 bits, round-to-nearest-even (finite inputs)
__device__ inline ushort f2b(float f) {
    uint32 x = __float_as_uint(f);
    uint32 r = x + 0x7fffu + ((x >> 16) & 1u);
    return (ushort)(r >> 16);
}
__device__ inline float blo(uint32 u) { return __uint_as_float(u << 16); }
__device__ inline float bhi(uint32 u) { return __uint_as_float(u & 0xffff0000u); }

__device__ inline short8 cvt8(const float* p) {
    float4 v0 = ((const float4*)p)[0];
    float4 v1 = ((const float4*)p)[1];
    short8 r;
    r[0] = (short)f2b(v0.x); r[1] = (short)f2b(v0.y);
    r[2] = (short)f2b(v0.z); r[3] = (short)f2b(v0.w);
    r[4] = (short)f2b(v1.x); r[5] = (short)f2b(v1.y);
    r[6] = (short)f2b(v1.z); r[7] = (short)f2b(v1.w);
    return r;
}

// ---------------- cast+transpose W -> WT bf16 [layer][n][k]; also zero cur ----------------
__global__ __launch_bounds__(256) void k_castw(const float* __restrict__ W1, const float* __restrict__ W2,
                                               const float* __restrict__ W3, ushort* __restrict__ WT,
                                               int* __restrict__ cur) {
    int i = blockIdx.x * blockDim.x + threadIdx.x;   // 3*16384
    if (i < NBUCK) cur[i] = 0;
    if (i >= 3 * NFEAT * NFEAT) return;
    int l = i >> 14;
    int j = i & 16383;
    int n = j >> 7;
    int k = j & 127;
    const float* W = (l == 0) ? W1 : (l == 1) ? W2 : W3;
    WT[i] = f2b(W[k * NFEAT + n]);   // WT[l][n*128+k] = W[k][n]
}

// ---------------- phase 1: scatter (blocks 0..390) || layer-1 GEMM (blocks 391..1172) ----------------
struct SMemScatter {
    int hist[NBUCK], lofs[NBUCK], gbase[NBUCK];
    int wsum[4];
    uint32 sortedP[SC_EDGES];   // 16 KB
    ushort sortedB[SC_EDGES];   //  8 KB
};

__global__ __launch_bounds__(512) void k_phase1(const int* __restrict__ src, const int* __restrict__ dst,
                                                int* __restrict__ cur, uint32* __restrict__ bbuf,
                                                const float* __restrict__ A, const ushort* __restrict__ WTl,
                                                ushort* __restrict__ C, int M) {
    __shared__ __align__(16) char smem[NFEAT * WT_STRIDE * 2];   // 34 KB >= sizeof(SMemScatter)
    int t = threadIdx.x;
    if (blockIdx.x < SC_BLOCKS) {
        // ================== scatter: single-pass ticketed counting sort ==================
        SMemScatter& S = *(SMemScatter*)smem;
        int e0 = blockIdx.x * SC_EDGES;
        int total = N_EDGES - e0; if (total > SC_EDGES) total = SC_EDGES; if (total < 0) total = 0;
        for (int i = t; i < NBUCK; i += 512) S.hist[i] = 0;
        __syncthreads();
        uint32 val[SC_EPT];
        int    meta[SC_EPT];    // (bucket << 13) | ticket
        #pragma unroll
        for (int k = 0; k < SC_EPT; ++k) {
            int i = t + k * 512;
            meta[k] = -1;
            if (i < total) {
                int s = src[e0 + i], d = dst[e0 + i];
                int b = d >> BSHIFT;
                int tk = atomicAdd(&S.hist[b], 1);
                val[k] = ((uint32)(d & (BNODES - 1)) << 17) | (uint32)s;
                meta[k] = (b << 13) | tk;
            }
        }
        __syncthreads();
        // scan of 391 bins on first 256 threads (2/thread) + per-bin global reservation
        int inc = 0, ts = 0, h0 = 0;
        if (t < 256) {
            int b0 = 2 * t, b1 = 2 * t + 1;
            h0 = (b0 < NBUCK) ? S.hist[b0] : 0;
            int h1 = (b1 < NBUCK) ? S.hist[b1] : 0;
            ts = h0 + h1;
            int lane = t & 63;
            inc = ts;
            #pragma unroll
            for (int d = 1; d < 64; d <<= 1) {
                int u = __shfl_up(inc, d, 64);
                if (lane >= d) inc += u;
            }
            if (lane == 63) S.wsum[t >> 6] = inc;
        }
        __syncthreads();
        if (t < 256) {
            int w = t >> 6;
            int wpre = 0;
            for (int i = 0; i < w; ++i) wpre += S.wsum[i];
            int run = wpre + inc - ts;
            int b0 = 2 * t, b1 = 2 * t + 1;
            int h1 = ts - h0;
            if (b0 < NBUCK) {
                S.lofs[b0] = run;
                if (h0) S.gbase[b0] = atomicAdd(&cur[b0], h0);
            }
            if (b1 < NBUCK) {
                S.lofs[b1] = run + h0;
                if (h1) S.gbase[b1] = atomicAdd(&cur[b1], h1);
            }
        }
        __syncthreads();
        #pragma unroll
        for (int k = 0; k < SC_EPT; ++k) {
            if (meta[k] >= 0) {
                int b = meta[k] >> 13;
                int p = S.lofs[b] + (meta[k] & 0x1FFF);
                S.sortedP[p] = val[k];
                S.sortedB[p] = (ushort)b;
            }
        }
        __syncthreads();
        for (int i = t; i < total; i += 512) {
            int b = S.sortedB[i];
            int addr = S.gbase[b] + (i - S.lofs[b]);
            if (addr < BCAP)
                bbuf[(size_t)b * BCAP + addr] = S.sortedP[i];
        }
    } else {
        // ================== layer-1 GEMM (fp32 A, cast fused) ==================
        ushort* sWT = (ushort*)smem;
        int gb = blockIdx.x - SC_BLOCKS;
        for (int i = t; i < NFEAT * 16; i += 512) {
            int n = i >> 4, c = i & 15;
            *(float4*)(sWT + n * WT_STRIDE + c * 8) = ((const float4*)WTl)[i];
        }
        int wave = t >> 6, lane = t & 63;
        int m0 = gb * 128 + wave * 16;
        int mRow = m0 + (lane & 15);
        if (mRow >= M) mRow = M - 1;
        int kg = lane >> 4;
        const float* Ap = A + (size_t)mRow * NFEAT + kg * 8;
        short8 a0 = cvt8(Ap);
        short8 a1 = cvt8(Ap + 32);
        short8 a2 = cvt8(Ap + 64);
        short8 a3 = cvt8(Ap + 96);
        __syncthreads();

        f32x4 acc[8];
        #pragma unroll
        for (int nt = 0; nt < 8; ++nt) acc[nt] = (f32x4){0.f, 0.f, 0.f, 0.f};
        #pragma unroll
        for (int nt = 0; nt < 8; ++nt) {
            int n = nt * 16 + (lane & 15);
            const short8* Bp = (const short8*)(sWT + n * WT_STRIDE + kg * 8);
            short8 b0 = Bp[0];
            short8 b1 = Bp[4];
            short8 b2 = Bp[8];
            short8 b3 = Bp[12];
            acc[nt] = __builtin_amdgcn_mfma_f32_16x16x32_bf16(a0, b0, acc[nt], 0, 0, 0);
            acc[nt] = __builtin_amdgcn_mfma_f32_16x16x32_bf16(a1, b1, acc[nt], 0, 0, 0);
            acc[nt] = __builtin_amdgcn_mfma_f32_16x16x32_bf16(a2, b2, acc[nt], 0, 0, 0);
            acc[nt] = __builtin_amdgcn_mfma_f32_16x16x32_bf16(a3, b3, acc[nt], 0, 0, 0);
        }
        __syncthreads();
        {
            int colBase = lane & 15;
            #pragma unroll
            for (int r = 0; r < 4; ++r) {
                int lr = wave * 16 + kg * 4 + r;
                #pragma unroll
                for (int nt = 0; nt < 8; ++nt)
                    sWT[lr * NFEAT + nt * 16 + colBase] = f2b(acc[nt][r]);
            }
        }
        __syncthreads();
        {
            int rowBase = gb * 128;
            const float4* sC4 = (const float4*)sWT;
            for (int i = t; i < 2048; i += 512) {
                int row = i >> 4;
                int gr = rowBase + row;
                if (gr < M) ((float4*)(C + (size_t)gr * NFEAT))[i & 15] = sC4[i];
            }
        }
    }
}

// ---------------- per-bucket ticketed counting sort -> CSR col + offsets + dinv ----------------
__global__ __launch_bounds__(256) void k_build(const uint32* __restrict__ bbuf, const int* __restrict__ cur,
                                               int* __restrict__ col, int* __restrict__ offsets,
                                               float* __restrict__ dinv) {
    int b = blockIdx.x;
    __shared__ int hist[BNODES], excl[BNODES];
    __shared__ int wsum[4], wtot[4];
    __shared__ int sorted[BCAP];              // 18 KB
    __shared__ int sBase, sTotal;
    int t = threadIdx.x;
    {
        int pre = 0, tot = 0;
        #pragma unroll
        for (int q = 0; q < 2; ++q) {
            int i = 2 * t + q;
            if (i < NBUCK) {
                int v = cur[i]; if (v > BCAP) v = BCAP;
                tot += v;
                if (i < b) pre += v;
            }
        }
        int lane = t & 63, w = t >> 6;
        #pragma unroll
        for (int d = 32; d > 0; d >>= 1) { pre += __shfl_down(pre, d, 64); tot += __shfl_down(tot, d, 64); }
        if (lane == 0) { wsum[w] = pre; wtot[w] = tot; }
        __syncthreads();
        if (t == 0) {
            sBase = wsum[0] + wsum[1] + wsum[2] + wsum[3];
            sTotal = wtot[0] + wtot[1] + wtot[2] + wtot[3];
        }
        hist[t] = 0;
    }
    __syncthreads();
    int base = sBase;
    if (b == NBUCK - 1 && t == 0) offsets[N_NODES] = sTotal;
    int cnt = cur[b]; if (cnt > BCAP) cnt = BCAP;
    const uint32* reg = bbuf + (size_t)b * BCAP;

    uint32 val[BD_EPT];
    int    meta[BD_EPT];   // (node << 16) | ticket
    #pragma unroll
    for (int k = 0; k < BD_EPT; ++k) {
        int i = t + k * 256;
        meta[k] = -1;
        if (i < cnt) {
            uint32 p = reg[i];
            int node = p >> 17;
            int tk = atomicAdd(&hist[node], 1);
            val[k] = p & 0x1FFFF;
            meta[k] = (node << 16) | tk;
        }
    }
    __syncthreads();
    {
        int c = hist[t];
        int lane = t & 63, w = t >> 6;
        int inc = c;
        #pragma unroll
        for (int d = 1; d < 64; d <<= 1) {
            int u = __shfl_up(inc, d, 64);
            if (lane >= d) inc += u;
        }
        if (lane == 63) wsum[w] = inc;
        __syncthreads();
        int wpre = 0;
        for (int i = 0; i < w; ++i) wpre += wsum[i];
        int e = wpre + inc - c;
        excl[t] = e;
        int node = (b << BSHIFT) + t;
        if (node < N_NODES) {
            offsets[node] = base + e;
            dinv[node] = rsqrtf((float)(c + 1));
        }
    }
    __syncthreads();
    #pragma unroll
    for (int k = 0; k < BD_EPT; ++k) {
        if (meta[k] >= 0) {
            int node = meta[k] >> 16;
            sorted[excl[node] + (meta[k] & 0xFFFF)] = (int)val[k];
        }
    }
    __syncthreads();
    for (int i = t; i < cnt; i += 256) col[base + i] = sorted[i];
}

// ---------------- bf16 MFMA GEMM (layers 2,3): C[M,128] = A[M,128] @ W ----------------
__global__ __launch_bounds__(512) void k_gemm(const ushort* __restrict__ A,
                                              const ushort* __restrict__ WTl,
                                              ushort* __restrict__ C, int M) {
    __shared__ ushort sWT[NFEAT * WT_STRIDE];   // 34 KB
    int t = threadIdx.x;
    for (int i = t; i < NFEAT * 16; i += 512) {
        int n = i >> 4, c = i & 15;
        *(float4*)(sWT + n * WT_STRIDE + c * 8) = ((const float4*)WTl)[i];
    }
    int wave = t >> 6, lane = t & 63;
    int m0 = blockIdx.x * 128 + wave * 16;
    int mRow = m0 + (lane & 15);
    if (mRow >= M) mRow = M - 1;
    int kg = lane >> 4;
    const short8* Ap = (const short8*)(A + (size_t)mRow * NFEAT + kg * 8);
    short8 a0 = Ap[0];
    short8 a1 = Ap[4];
    short8 a2 = Ap[8];
    short8 a3 = Ap[12];
    __syncthreads();

    f32x4 acc[8];
    #pragma unroll
    for (int nt = 0; nt < 8; ++nt) acc[nt] = (f32x4){0.f, 0.f, 0.f, 0.f};
    #pragma unroll
    for (int nt = 0; nt < 8; ++nt) {
        int n = nt * 16 + (lane & 15);
        const short8* Bp = (const short8*)(sWT + n * WT_STRIDE + kg * 8);
        short8 b0 = Bp[0];
        short8 b1 = Bp[4];
        short8 b2 = Bp[8];
        short8 b3 = Bp[12];
        acc[nt] = __builtin_amdgcn_mfma_f32_16x16x32_bf16(a0, b0, acc[nt], 0, 0, 0);
        acc[nt] = __builtin_amdgcn_mfma_f32_16x16x32_bf16(a1, b1, acc[nt], 0, 0, 0);
        acc[nt] = __builtin_amdgcn_mfma_f32_16x16x32_bf16(a2, b2, acc[nt], 0, 0, 0);
        acc[nt] = __builtin_amdgcn_mfma_f32_16x16x32_bf16(a3, b3, acc[nt], 0, 0, 0);
    }
    __syncthreads();
    {
        int colBase = lane & 15;
        #pragma unroll
        for (int r = 0; r < 4; ++r) {
            int lr = wave * 16 + kg * 4 + r;
            #pragma unroll
            for (int nt = 0; nt < 8; ++nt)
                sWT[lr * NFEAT + nt * 16 + colBase] = f2b(acc[nt][r]);
        }
    }
    __syncthreads();
    {
        int rowBase = blockIdx.x * 128;
        const float4* sC4 = (const float4*)sWT;
        for (int i = t; i < 2048; i += 512) {
            int row = i >> 4;
            int gr = rowBase + row;
            if (gr < M) ((float4*)(C + (size_t)gr * NFEAT))[i & 15] = sC4[i];
        }
    }
}

// ---------------- aggregation core: 4 nodes per wave (one per 16-lane group) ----------------
// Each 16-lane group owns node n = wid*4 + half. Accumulators are group-local, so no
// cross-group reduction shfls are needed and the final store is fully lane-active
// (wave stores 4 consecutive 256B rows = 1KB contiguous). Loop runs to the wave-max
// degree; groups past their own degree gather with zero weight (clamped to col 0 = hot line).
#define AGG_GROUP4 \
    int half = lane >> 4; \
    int fl = lane & 15; \
    float dn = dinv[n]; \
    int e0 = off[n], e1 = off[n + 1]; \
    int deg = e1 - e0; \
    int maxd = deg; \
    { int u16 = __shfl_xor(maxd, 16, 64); if (u16 > maxd) maxd = u16; \
      int u32 = __shfl_xor(maxd, 32, 64); if (u32 > maxd) maxd = u32; } \
    const uint4* XW4 = (const uint4*)XWu; \
    uint4 sv = XW4[(size_t)n * 16 + fl]; \
    float ws = dn * dn; \
    float a0 = ws * blo(sv.x), a1 = ws * bhi(sv.x); \
    float a2 = ws * blo(sv.y), a3 = ws * bhi(sv.y); \
    float a4 = ws * blo(sv.z), a5 = ws * bhi(sv.z); \
    float a6 = ws * blo(sv.w), a7 = ws * bhi(sv.w); \
    for (int base = 0; base < maxd; base += 16) { \
        int cm = 0; float wm = 0.f; \
        if (base + fl < deg) { cm = col[e0 + base + fl]; wm = dn * dinv[cm]; } \
        int lim = maxd - base; if (lim > 16) lim = 16; \
        int j = 0; \
        for (; j + 4 <= lim; j += 4) { \
            uint4 u[4]; float w[4]; \
            _Pragma("unroll") \
            for (int p = 0; p < 4; ++p) { \
                int sl = (half << 4) + j + p; \
                int cc = __shfl(cm, sl, 64); \
                w[p] = __shfl(wm, sl, 64); \
                u[p] = XW4[(size_t)cc * 16 + fl]; \
            } \
            _Pragma("unroll") \
            for (int p = 0; p < 4; ++p) { \
                a0 = fmaf(w[p], blo(u[p].x), a0); a1 = fmaf(w[p], bhi(u[p].x), a1); \
                a2 = fmaf(w[p], blo(u[p].y), a2); a3 = fmaf(w[p], bhi(u[p].y), a3); \
                a4 = fmaf(w[p], blo(u[p].z), a4); a5 = fmaf(w[p], bhi(u[p].z), a5); \
                a6 = fmaf(w[p], blo(u[p].w), a6); a7 = fmaf(w[p], bhi(u[p].w), a7); \
            } \
        } \
        for (; j < lim; ++j) { \
            int sl = (half << 4) + j; \
            int cc = __shfl(cm, sl, 64); \
            float ww = __shfl(wm, sl, 64); \
            uint4 u = XW4[(size_t)cc * 16 + fl]; \
            a0 = fmaf(ww, blo(u.x), a0); a1 = fmaf(ww, bhi(u.x), a1); \
            a2 = fmaf(ww, blo(u.y), a2); a3 = fmaf(ww, bhi(u.y), a3); \
            a4 = fmaf(ww, blo(u.z), a4); a5 = fmaf(ww, bhi(u.z), a5); \
            a6 = fmaf(ww, blo(u.w), a6); a7 = fmaf(ww, bhi(u.w), a7); \
        } \
    }

__global__ __launch_bounds__(256) void k_agg(const uint32* __restrict__ XWu, const int* __restrict__ col,
                                             const int* __restrict__ off, const float* __restrict__ dinv,
                                             const float* __restrict__ bias, uint32* __restrict__ Hu) {
    int wid = (blockIdx.x * blockDim.x + threadIdx.x) >> 6;
    int lane = threadIdx.x & 63;
    int n = (wid << 2) + (lane >> 4);
    if (n >= N_NODES) return;
    AGG_GROUP4
    float4 bb0 = ((const float4*)bias)[2 * fl];
    float4 bb1 = ((const float4*)bias)[2 * fl + 1];
    float r0 = fmaxf(a0 + bb0.x, 0.f), r1 = fmaxf(a1 + bb0.y, 0.f);
    float r2 = fmaxf(a2 + bb0.z, 0.f), r3 = fmaxf(a3 + bb0.w, 0.f);
    float r4 = fmaxf(a4 + bb1.x, 0.f), r5 = fmaxf(a5 + bb1.y, 0.f);
    float r6 = fmaxf(a6 + bb1.z, 0.f), r7 = fmaxf(a7 + bb1.w, 0.f);
    uint4 o;
    o.x = (uint32)f2b(r0) | ((uint32)f2b(r1) << 16);
    o.y = (uint32)f2b(r2) | ((uint32)f2b(r3) << 16);
    o.z = (uint32)f2b(r4) | ((uint32)f2b(r5) << 16);
    o.w = (uint32)f2b(r6) | ((uint32)f2b(r7) << 16);
    ((uint4*)Hu)[(size_t)n * 16 + fl] = o;
}

__global__ __launch_bounds__(256) void k_agg_fc(const uint32* __restrict__ XWu, const int* __restrict__ col,
                                                const int* __restrict__ off, const float* __restrict__ dinv,
                                                const float* __restrict__ bias, const float* __restrict__ Wfc,
                                                float* __restrict__ nodeS) {
    int wid = (blockIdx.x * blockDim.x + threadIdx.x) >> 6;
    int lane = threadIdx.x & 63;
    int n = (wid << 2) + (lane >> 4);
    if (n >= N_NODES) return;
    AGG_GROUP4
    float4 bb0 = ((const float4*)bias)[2 * fl];
    float4 bb1 = ((const float4*)bias)[2 * fl + 1];
    float4 wf0 = ((const float4*)Wfc)[2 * fl];
    float4 wf1 = ((const float4*)Wfc)[2 * fl + 1];
    float s = fmaxf(a0 + bb0.x, 0.f) * wf0.x + fmaxf(a1 + bb0.y, 0.f) * wf0.y
            + fmaxf(a2 + bb0.z, 0.f) * wf0.z + fmaxf(a3 + bb0.w, 0.f) * wf0.w
            + fmaxf(a4 + bb1.x, 0.f) * wf1.x + fmaxf(a5 + bb1.y, 0.f) * wf1.y
            + fmaxf(a6 + bb1.z, 0.f) * wf1.z + fmaxf(a7 + bb1.w, 0.f) * wf1.w;
    // reduce within the 16-lane group (xor distances 8/4/2/1 stay inside the group)
    s += __shfl_xor(s, 8, 64);
    s += __shfl_xor(s, 4, 64);
    s += __shfl_xor(s, 2, 64);
    s += __shfl_xor(s, 1, 64);
    if (fl == 0) nodeS[n] = s;
}

// ---------------- segment mean over sorted batch + bias (one block per graph) ----------------
__device__ inline int lower_bound_dev(const int* a, int n, int key) {
    int lo = 0, hi = n;
    while (lo < hi) {
        int mid = (lo + hi) >> 1;
        if (a[mid] < key) lo = mid + 1; else hi = mid;
    }
    return lo;
}

__global__ __launch_bounds__(256) void k_pool(const float* __restrict__ nodeS, const int* __restrict__ batch,
                                              const float* __restrict__ bfc, float* __restrict__ out) {
    int g = blockIdx.x;
    int t = threadIdx.x;
    int lo = lower_bound_dev(batch, N_NODES, g);
    int hi = lower_bound_dev(batch, N_NODES, g + 1);
    float s = 0.f;
    for (int i = lo + t; i < hi; i += 256) s += nodeS[i];
    for (int d = 32; d > 0; d >>= 1) s += __shfl_down(s, d, 64);
    __shared__ float ws[4];
    int lane = t & 63, w = t >> 6;
    if (lane == 0) ws[w] = s;
    __syncthreads();
    if (t == 0) {
        float tot = ws[0] + ws[1] + ws[2] + ws[3];
        float cnt = (float)(hi - lo);
        out[g] = tot / fmaxf(cnt, 1.0f) + bfc[0];
    }
}

// ---------------- launch ----------------
extern "C" void kernel_launch(void* const* d_in, const int* in_sizes, int n_in,
                              void* d_out, int out_size, void* d_ws, size_t ws_size,
                              hipStream_t stream) {
    const float* x    = (const float*)d_in[0];
    const int*   ei   = (const int*)d_in[1];     // [2, E] : row0 = src, row1 = dst
    const int*   batch= (const int*)d_in[2];
    const float* W1   = (const float*)d_in[3];
    const float* b1   = (const float*)d_in[4];
    const float* W2   = (const float*)d_in[5];
    const float* b2   = (const float*)d_in[6];
    const float* W3   = (const float*)d_in[7];
    const float* b3   = (const float*)d_in[8];
    const float* Wfc  = (const float*)d_in[9];
    const float* bfc  = (const float*)d_in[10];
    float* out = (float*)d_out;

    const int* src = ei;
    const int* dst = ei + N_EDGES;

    // carve workspace (256B-aligned)
    char* p = (char*)d_ws;
    auto carve = [&](size_t bytes) { void* r = (void*)p; p += (bytes + 255) & ~(size_t)255; return r; };
    int*    cur       = (int*)   carve(sizeof(int) * NBUCK);
    uint32* bbuf      = (uint32*)carve(sizeof(uint32) * (size_t)NBUCK * BCAP);            // 7.2 MB
    float*  dinv      = (float*) carve(sizeof(float) * N_NODES);
    int*    offsets   = (int*)   carve(sizeof(int) * (N_NODES + 1));
    int*    col       = (int*)   carve(sizeof(int) * N_EDGES);
    ushort* XW        = (ushort*)carve(sizeof(short) * (size_t)N_NODES * NFEAT);
    ushort* H         = (ushort*)carve(sizeof(short) * (size_t)N_NODES * NFEAT);
    ushort* WT        = (ushort*)carve(sizeof(short) * 3 * NFEAT * NFEAT);
    float*  nodeS     = (float*) carve(sizeof(float) * N_NODES);

    const int aggBlocks = (N_NODES + 15) / 16;   // 4 nodes/wave * 4 waves/block = 16 nodes/block

    k_castw<<<(3 * NFEAT * NFEAT + 255) / 256, 256, 0, stream>>>(W1, W2, W3, WT, cur);
    // phase 1: scatter || layer-1 GEMM (independent work co-scheduled)  -> XW = x @ W1
    k_phase1<<<SC_BLOCKS + GEMM_BLOCKS, 512, 0, stream>>>(src, dst, cur, bbuf, x, WT, XW, N_NODES);
    k_build<<<NBUCK, 256, 0, stream>>>(bbuf, cur, col, offsets, dinv);

    k_agg<<<aggBlocks, 256, 0, stream>>>((const uint32*)XW, col, offsets, dinv, b1, (uint32*)H);
    // layer 2
    k_gemm<<<GEMM_BLOCKS, 512, 0, stream>>>(H, WT + NFEAT * NFEAT, XW, N_NODES);
    k_agg<<<aggBlocks, 256, 0, stream>>>((const uint32*)XW, col, offsets, dinv, b2, (uint32*)H);
    // layer 3
    k_gemm<<<GEMM_BLOCKS, 512, 0, stream>>>(H, WT + 2 * NFEAT * NFEAT, XW, N_NODES);
    k_agg_fc<<<aggBlocks, 256, 0, stream>>>((const uint32*)XW, col, offsets, dinv, b3, Wfc, nodeS);

    k_pool<<<N_GRAPHS, 256, 0, stream>>>(nodeS, batch, bfc, out);
}

// Round 4
// 354.245 us; speedup vs baseline: 1.2693x; 1.0092x over previous
//
#include <hip/hip_runtime.h>

#define N_NODES   100000
#define N_EDGES   1600000
#define NFEAT     128
#define N_GRAPHS  1024

// ---- bucketed CSR build ----
#define BSHIFT  8
#define BNODES  256
#define NBUCK   391                  // ceil(100000 / 256)
#define BCAP    4608                 // mean 4096 + 8 sigma
#define SC_EDGES 4096
#define SC_EPT   8                   // edges per thread (4096/512)
#define SC_BLOCKS 391                // ceil(1.6M / 4096)
#define BD_EPT   18                  // ceil(BCAP/256)

#define WT_STRIDE 136
#define GEMM_BLOCKS 782              // ceil(100000/128)

typedef unsigned int uint32;
typedef unsigned short ushort;
typedef __attribute__((ext_vector_type(8))) short short8;   // 8 bf16 (4 VGPRs)
typedef __attribute__((ext_vector_type(4))) float f32x4;

// fp32 -> bf16 bits, round-to-nearest-even (finite inputs)
__device__ inline ushort f2b(float f) {
    uint32 x = __float_as_uint(f);
    uint32 r = x + 0x7fffu + ((x >> 16) & 1u);
    return (ushort)(r >> 16);
}
__device__ inline float blo(uint32 u) { return __uint_as_float(u << 16); }
__device__ inline float bhi(uint32 u) { return __uint_as_float(u & 0xffff0000u); }

__device__ inline short8 cvt8(const float* p) {
    float4 v0 = ((const float4*)p)[0];
    float4 v1 = ((const float4*)p)[1];
    short8 r;
    r[0] = (short)f2b(v0.x); r[1] = (short)f2b(v0.y);
    r[2] = (short)f2b(v0.z); r[3] = (short)f2b(v0.w);
    r[4] = (short)f2b(v1.x); r[5] = (short)f2b(v1.y);
    r[6] = (short)f2b(v1.z); r[7] = (short)f2b(v1.w);
    return r;
}

// ---------------- cast+transpose W -> WT bf16 [layer][n][k]; also zero cur ----------------
__global__ __launch_bounds__(256) void k_castw(const float* __restrict__ W1, const float* __restrict__ W2,
                                               const float* __restrict__ W3, ushort* __restrict__ WT,
                                               int* __restrict__ cur) {
    int i = blockIdx.x * blockDim.x + threadIdx.x;   // 3*16384
    if (i < NBUCK) cur[i] = 0;
    if (i >= 3 * NFEAT * NFEAT) return;
    int l = i >> 14;
    int j = i & 16383;
    int n = j >> 7;
    int k = j & 127;
    const float* W = (l == 0) ? W1 : (l == 1) ? W2 : W3;
    WT[i] = f2b(W[k * NFEAT + n]);   // WT[l][n*128+k] = W[k][n]
}

// ---------------- phase 1: scatter (blocks 0..390) || layer-1 GEMM (blocks 391..1172) ----------------
struct SMemScatter {
    int hist[NBUCK], lofs[NBUCK], gbase[NBUCK];
    int wsum[4];
    uint32 sortedP[SC_EDGES];   // 16 KB
    ushort sortedB[SC_EDGES];   //  8 KB
};

__global__ __launch_bounds__(512) void k_phase1(const int* __restrict__ src, const int* __restrict__ dst,
                                                int* __restrict__ cur, uint32* __restrict__ bbuf,
                                                const float* __restrict__ A, const ushort* __restrict__ WTl,
                                                ushort* __restrict__ C, int M) {
    __shared__ __align__(16) char smem[NFEAT * WT_STRIDE * 2];   // 34 KB >= sizeof(SMemScatter)
    int t = threadIdx.x;
    if (blockIdx.x < SC_BLOCKS) {
        // ================== scatter: single-pass ticketed counting sort ==================
        SMemScatter& S = *(SMemScatter*)smem;
        int e0 = blockIdx.x * SC_EDGES;
        int total = N_EDGES - e0; if (total > SC_EDGES) total = SC_EDGES; if (total < 0) total = 0;
        for (int i = t; i < NBUCK; i += 512) S.hist[i] = 0;
        __syncthreads();
        uint32 val[SC_EPT];
        int    meta[SC_EPT];    // (bucket << 13) | ticket
        #pragma unroll
        for (int k = 0; k < SC_EPT; ++k) {
            int i = t + k * 512;
            meta[k] = -1;
            if (i < total) {
                int s = src[e0 + i], d = dst[e0 + i];
                int b = d >> BSHIFT;
                int tk = atomicAdd(&S.hist[b], 1);
                val[k] = ((uint32)(d & (BNODES - 1)) << 17) | (uint32)s;
                meta[k] = (b << 13) | tk;
            }
        }
        __syncthreads();
        // scan of 391 bins on first 256 threads (2/thread) + per-bin global reservation
        int inc = 0, ts = 0, h0 = 0;
        if (t < 256) {
            int b0 = 2 * t, b1 = 2 * t + 1;
            h0 = (b0 < NBUCK) ? S.hist[b0] : 0;
            int h1 = (b1 < NBUCK) ? S.hist[b1] : 0;
            ts = h0 + h1;
            int lane = t & 63;
            inc = ts;
            #pragma unroll
            for (int d = 1; d < 64; d <<= 1) {
                int u = __shfl_up(inc, d, 64);
                if (lane >= d) inc += u;
            }
            if (lane == 63) S.wsum[t >> 6] = inc;
        }
        __syncthreads();
        if (t < 256) {
            int w = t >> 6;
            int wpre = 0;
            for (int i = 0; i < w; ++i) wpre += S.wsum[i];
            int run = wpre + inc - ts;
            int b0 = 2 * t, b1 = 2 * t + 1;
            int h1 = ts - h0;
            if (b0 < NBUCK) {
                S.lofs[b0] = run;
                if (h0) S.gbase[b0] = atomicAdd(&cur[b0], h0);
            }
            if (b1 < NBUCK) {
                S.lofs[b1] = run + h0;
                if (h1) S.gbase[b1] = atomicAdd(&cur[b1], h1);
            }
        }
        __syncthreads();
        #pragma unroll
        for (int k = 0; k < SC_EPT; ++k) {
            if (meta[k] >= 0) {
                int b = meta[k] >> 13;
                int p = S.lofs[b] + (meta[k] & 0x1FFF);
                S.sortedP[p] = val[k];
                S.sortedB[p] = (ushort)b;
            }
        }
        __syncthreads();
        for (int i = t; i < total; i += 512) {
            int b = S.sortedB[i];
            int addr = S.gbase[b] + (i - S.lofs[b]);
            if (addr < BCAP)
                bbuf[(size_t)b * BCAP + addr] = S.sortedP[i];
        }
    } else {
        // ================== layer-1 GEMM (fp32 A, cast fused) ==================
        ushort* sWT = (ushort*)smem;
        int gb = blockIdx.x - SC_BLOCKS;
        for (int i = t; i < NFEAT * 16; i += 512) {
            int n = i >> 4, c = i & 15;
            *(float4*)(sWT + n * WT_STRIDE + c * 8) = ((const float4*)WTl)[i];
        }
        int wave = t >> 6, lane = t & 63;
        int m0 = gb * 128 + wave * 16;
        int mRow = m0 + (lane & 15);
        if (mRow >= M) mRow = M - 1;
        int kg = lane >> 4;
        const float* Ap = A + (size_t)mRow * NFEAT + kg * 8;
        short8 a0 = cvt8(Ap);
        short8 a1 = cvt8(Ap + 32);
        short8 a2 = cvt8(Ap + 64);
        short8 a3 = cvt8(Ap + 96);
        __syncthreads();

        f32x4 acc[8];
        #pragma unroll
        for (int nt = 0; nt < 8; ++nt) acc[nt] = (f32x4){0.f, 0.f, 0.f, 0.f};
        #pragma unroll
        for (int nt = 0; nt < 8; ++nt) {
            int n = nt * 16 + (lane & 15);
            const short8* Bp = (const short8*)(sWT + n * WT_STRIDE + kg * 8);
            short8 b0 = Bp[0];
            short8 b1 = Bp[4];
            short8 b2 = Bp[8];
            short8 b3 = Bp[12];
            acc[nt] = __builtin_amdgcn_mfma_f32_16x16x32_bf16(a0, b0, acc[nt], 0, 0, 0);
            acc[nt] = __builtin_amdgcn_mfma_f32_16x16x32_bf16(a1, b1, acc[nt], 0, 0, 0);
            acc[nt] = __builtin_amdgcn_mfma_f32_16x16x32_bf16(a2, b2, acc[nt], 0, 0, 0);
            acc[nt] = __builtin_amdgcn_mfma_f32_16x16x32_bf16(a3, b3, acc[nt], 0, 0, 0);
        }
        __syncthreads();
        {
            int colBase = lane & 15;
            #pragma unroll
            for (int r = 0; r < 4; ++r) {
                int lr = wave * 16 + kg * 4 + r;
                #pragma unroll
                for (int nt = 0; nt < 8; ++nt)
                    sWT[lr * NFEAT + nt * 16 + colBase] = f2b(acc[nt][r]);
            }
        }
        __syncthreads();
        {
            int rowBase = gb * 128;
            const float4* sC4 = (const float4*)sWT;
            for (int i = t; i < 2048; i += 512) {
                int row = i >> 4;
                int gr = rowBase + row;
                if (gr < M) ((float4*)(C + (size_t)gr * NFEAT))[i & 15] = sC4[i];
            }
        }
    }
}

// ---------------- per-bucket ticketed counting sort -> CSR col + offsets + dinv ----------------
__global__ __launch_bounds__(256) void k_build(const uint32* __restrict__ bbuf, const int* __restrict__ cur,
                                               int* __restrict__ col, int* __restrict__ offsets,
                                               float* __restrict__ dinv) {
    int b = blockIdx.x;
    __shared__ int hist[BNODES], excl[BNODES];
    __shared__ int wsum[4], wtot[4];
    __shared__ int sorted[BCAP];              // 18 KB
    __shared__ int sBase, sTotal;
    int t = threadIdx.x;
    {
        int pre = 0, tot = 0;
        #pragma unroll
        for (int q = 0; q < 2; ++q) {
            int i = 2 * t + q;
            if (i < NBUCK) {
                int v = cur[i]; if (v > BCAP) v = BCAP;
                tot += v;
                if (i < b) pre += v;
            }
        }
        int lane = t & 63, w = t >> 6;
        #pragma unroll
        for (int d = 32; d > 0; d >>= 1) { pre += __shfl_down(pre, d, 64); tot += __shfl_down(tot, d, 64); }
        if (lane == 0) { wsum[w] = pre; wtot[w] = tot; }
        __syncthreads();
        if (t == 0) {
            sBase = wsum[0] + wsum[1] + wsum[2] + wsum[3];
            sTotal = wtot[0] + wtot[1] + wtot[2] + wtot[3];
        }
        hist[t] = 0;
    }
    __syncthreads();
    int base = sBase;
    if (b == NBUCK - 1 && t == 0) offsets[N_NODES] = sTotal;
    int cnt = cur[b]; if (cnt > BCAP) cnt = BCAP;
    const uint32* reg = bbuf + (size_t)b * BCAP;

    uint32 val[BD_EPT];
    int    meta[BD_EPT];   // (node << 16) | ticket
    #pragma unroll
    for (int k = 0; k < BD_EPT; ++k) {
        int i = t + k * 256;
        meta[k] = -1;
        if (i < cnt) {
            uint32 p = reg[i];
            int node = p >> 17;
            int tk = atomicAdd(&hist[node], 1);
            val[k] = p & 0x1FFFF;
            meta[k] = (node << 16) | tk;
        }
    }
    __syncthreads();
    {
        int c = hist[t];
        int lane = t & 63, w = t >> 6;
        int inc = c;
        #pragma unroll
        for (int d = 1; d < 64; d <<= 1) {
            int u = __shfl_up(inc, d, 64);
            if (lane >= d) inc += u;
        }
        if (lane == 63) wsum[w] = inc;
        __syncthreads();
        int wpre = 0;
        for (int i = 0; i < w; ++i) wpre += wsum[i];
        int e = wpre + inc - c;
        excl[t] = e;
        int node = (b << BSHIFT) + t;
        if (node < N_NODES) {
            offsets[node] = base + e;
            dinv[node] = rsqrtf((float)(c + 1));
        }
    }
    __syncthreads();
    #pragma unroll
    for (int k = 0; k < BD_EPT; ++k) {
        if (meta[k] >= 0) {
            int node = meta[k] >> 16;
            sorted[excl[node] + (meta[k] & 0xFFFF)] = (int)val[k];
        }
    }
    __syncthreads();
    for (int i = t; i < cnt; i += 256) col[base + i] = sorted[i];
}

// ---------------- bf16 MFMA GEMM (layers 2,3): C[M,128] = A[M,128] @ W ----------------
__global__ __launch_bounds__(512) void k_gemm(const ushort* __restrict__ A,
                                              const ushort* __restrict__ WTl,
                                              ushort* __restrict__ C, int M) {
    __shared__ ushort sWT[NFEAT * WT_STRIDE];   // 34 KB
    int t = threadIdx.x;
    for (int i = t; i < NFEAT * 16; i += 512) {
        int n = i >> 4, c = i & 15;
        *(float4*)(sWT + n * WT_STRIDE + c * 8) = ((const float4*)WTl)[i];
    }
    int wave = t >> 6, lane = t & 63;
    int m0 = blockIdx.x * 128 + wave * 16;
    int mRow = m0 + (lane & 15);
    if (mRow >= M) mRow = M - 1;
    int kg = lane >> 4;
    const short8* Ap = (const short8*)(A + (size_t)mRow * NFEAT + kg * 8);
    short8 a0 = Ap[0];
    short8 a1 = Ap[4];
    short8 a2 = Ap[8];
    short8 a3 = Ap[12];
    __syncthreads();

    f32x4 acc[8];
    #pragma unroll
    for (int nt = 0; nt < 8; ++nt) acc[nt] = (f32x4){0.f, 0.f, 0.f, 0.f};
    #pragma unroll
    for (int nt = 0; nt < 8; ++nt) {
        int n = nt * 16 + (lane & 15);
        const short8* Bp = (const short8*)(sWT + n * WT_STRIDE + kg * 8);
        short8 b0 = Bp[0];
        short8 b1 = Bp[4];
        short8 b2 = Bp[8];
        short8 b3 = Bp[12];
        acc[nt] = __builtin_amdgcn_mfma_f32_16x16x32_bf16(a0, b0, acc[nt], 0, 0, 0);
        acc[nt] = __builtin_amdgcn_mfma_f32_16x16x32_bf16(a1, b1, acc[nt], 0, 0, 0);
        acc[nt] = __builtin_amdgcn_mfma_f32_16x16x32_bf16(a2, b2, acc[nt], 0, 0, 0);
        acc[nt] = __builtin_amdgcn_mfma_f32_16x16x32_bf16(a3, b3, acc[nt], 0, 0, 0);
    }
    __syncthreads();
    {
        int colBase = lane & 15;
        #pragma unroll
        for (int r = 0; r < 4; ++r) {
            int lr = wave * 16 + kg * 4 + r;
            #pragma unroll
            for (int nt = 0; nt < 8; ++nt)
                sWT[lr * NFEAT + nt * 16 + colBase] = f2b(acc[nt][r]);
        }
    }
    __syncthreads();
    {
        int rowBase = blockIdx.x * 128;
        const float4* sC4 = (const float4*)sWT;
        for (int i = t; i < 2048; i += 512) {
            int row = i >> 4;
            int gr = rowBase + row;
            if (gr < M) ((float4*)(C + (size_t)gr * NFEAT))[i & 15] = sC4[i];
        }
    }
}

// ---------------- aggregation core: 4 nodes per wave, 8-wide gather pipeline ----------------
// Each 16-lane group owns node n = wid*4 + half. Group-local accumulators (no cross-group
// reduction), fully lane-active contiguous stores. Deep pipeline: 8 uint4 gathers in flight;
// next chunk's col/dinv prefetched under current chunk's FMAs; no serial tail loop (overflow
// slots carry wm=0/cm=0 by construction: base+slot >= maxd >= deg for slot >= lim).
#define AGG_GROUP4 \
    int half = lane >> 4; \
    int fl = lane & 15; \
    float dn = dinv[n]; \
    int e0 = off[n], e1 = off[n + 1]; \
    int deg = e1 - e0; \
    int maxd = deg; \
    { int u16 = __shfl_xor(maxd, 16, 64); if (u16 > maxd) maxd = u16; \
      int u32 = __shfl_xor(maxd, 32, 64); if (u32 > maxd) maxd = u32; } \
    const uint4* XW4 = (const uint4*)XWu; \
    uint4 sv = XW4[(size_t)n * 16 + fl]; \
    float ws = dn * dn; \
    float a0 = ws * blo(sv.x), a1 = ws * bhi(sv.x); \
    float a2 = ws * blo(sv.y), a3 = ws * bhi(sv.y); \
    float a4 = ws * blo(sv.z), a5 = ws * bhi(sv.z); \
    float a6 = ws * blo(sv.w), a7 = ws * bhi(sv.w); \
    int cm = 0; float wm = 0.f; \
    if (fl < deg) { cm = col[e0 + fl]; wm = dn * dinv[cm]; } \
    for (int base = 0; base < maxd; base += 16) { \
        int nb = base + 16; \
        int cmn = 0; float wmn = 0.f; \
        if (nb + fl < deg) { cmn = col[e0 + nb + fl]; wmn = dn * dinv[cmn]; } \
        int lim = maxd - base; if (lim > 16) lim = 16; \
        for (int j = 0; j < lim; j += 8) { \
            uint4 u[8]; float w[8]; \
            _Pragma("unroll") \
            for (int p = 0; p < 8; ++p) { \
                int sl = (half << 4) + j + p; \
                int cc = __shfl(cm, sl, 64); \
                w[p] = __shfl(wm, sl, 64); \
                u[p] = XW4[(size_t)cc * 16 + fl]; \
            } \
            _Pragma("unroll") \
            for (int p = 0; p < 8; ++p) { \
                a0 = fmaf(w[p], blo(u[p].x), a0); a1 = fmaf(w[p], bhi(u[p].x), a1); \
                a2 = fmaf(w[p], blo(u[p].y), a2); a3 = fmaf(w[p], bhi(u[p].y), a3); \
                a4 = fmaf(w[p], blo(u[p].z), a4); a5 = fmaf(w[p], bhi(u[p].z), a5); \
                a6 = fmaf(w[p], blo(u[p].w), a6); a7 = fmaf(w[p], bhi(u[p].w), a7); \
            } \
        } \
        cm = cmn; wm = wmn; \
    }

__global__ __launch_bounds__(256) void k_agg(const uint32* __restrict__ XWu, const int* __restrict__ col,
                                             const int* __restrict__ off, const float* __restrict__ dinv,
                                             const float* __restrict__ bias, uint32* __restrict__ Hu) {
    int wid = (blockIdx.x * blockDim.x + threadIdx.x) >> 6;
    int lane = threadIdx.x & 63;
    int n = (wid << 2) + (lane >> 4);
    if (n >= N_NODES) return;
    AGG_GROUP4
    float4 bb0 = ((const float4*)bias)[2 * fl];
    float4 bb1 = ((const float4*)bias)[2 * fl + 1];
    float r0 = fmaxf(a0 + bb0.x, 0.f), r1 = fmaxf(a1 + bb0.y, 0.f);
    float r2 = fmaxf(a2 + bb0.z, 0.f), r3 = fmaxf(a3 + bb0.w, 0.f);
    float r4 = fmaxf(a4 + bb1.x, 0.f), r5 = fmaxf(a5 + bb1.y, 0.f);
    float r6 = fmaxf(a6 + bb1.z, 0.f), r7 = fmaxf(a7 + bb1.w, 0.f);
    uint4 o;
    o.x = (uint32)f2b(r0) | ((uint32)f2b(r1) << 16);
    o.y = (uint32)f2b(r2) | ((uint32)f2b(r3) << 16);
    o.z = (uint32)f2b(r4) | ((uint32)f2b(r5) << 16);
    o.w = (uint32)f2b(r6) | ((uint32)f2b(r7) << 16);
    ((uint4*)Hu)[(size_t)n * 16 + fl] = o;
}

__global__ __launch_bounds__(256) void k_agg_fc(const uint32* __restrict__ XWu, const int* __restrict__ col,
                                                const int* __restrict__ off, const float* __restrict__ dinv,
                                                const float* __restrict__ bias, const float* __restrict__ Wfc,
                                                float* __restrict__ nodeS) {
    int wid = (blockIdx.x * blockDim.x + threadIdx.x) >> 6;
    int lane = threadIdx.x & 63;
    int n = (wid << 2) + (lane >> 4);
    if (n >= N_NODES) return;
    AGG_GROUP4
    float4 bb0 = ((const float4*)bias)[2 * fl];
    float4 bb1 = ((const float4*)bias)[2 * fl + 1];
    float4 wf0 = ((const float4*)Wfc)[2 * fl];
    float4 wf1 = ((const float4*)Wfc)[2 * fl + 1];
    float s = fmaxf(a0 + bb0.x, 0.f) * wf0.x + fmaxf(a1 + bb0.y, 0.f) * wf0.y
            + fmaxf(a2 + bb0.z, 0.f) * wf0.z + fmaxf(a3 + bb0.w, 0.f) * wf0.w
            + fmaxf(a4 + bb1.x, 0.f) * wf1.x + fmaxf(a5 + bb1.y, 0.f) * wf1.y
            + fmaxf(a6 + bb1.z, 0.f) * wf1.z + fmaxf(a7 + bb1.w, 0.f) * wf1.w;
    // reduce within the 16-lane group (xor distances 8/4/2/1 stay inside the group)
    s += __shfl_xor(s, 8, 64);
    s += __shfl_xor(s, 4, 64);
    s += __shfl_xor(s, 2, 64);
    s += __shfl_xor(s, 1, 64);
    if (fl == 0) nodeS[n] = s;
}

// ---------------- segment mean over sorted batch + bias (one block per graph) ----------------
__device__ inline int lower_bound_dev(const int* a, int n, int key) {
    int lo = 0, hi = n;
    while (lo < hi) {
        int mid = (lo + hi) >> 1;
        if (a[mid] < key) lo = mid + 1; else hi = mid;
    }
    return lo;
}

__global__ __launch_bounds__(256) void k_pool(const float* __restrict__ nodeS, const int* __restrict__ batch,
                                              const float* __restrict__ bfc, float* __restrict__ out) {
    int g = blockIdx.x;
    int t = threadIdx.x;
    int lo = lower_bound_dev(batch, N_NODES, g);
    int hi = lower_bound_dev(batch, N_NODES, g + 1);
    float s = 0.f;
    for (int i = lo + t; i < hi; i += 256) s += nodeS[i];
    for (int d = 32; d > 0; d >>= 1) s += __shfl_down(s, d, 64);
    __shared__ float ws[4];
    int lane = t & 63, w = t >> 6;
    if (lane == 0) ws[w] = s;
    __syncthreads();
    if (t == 0) {
        float tot = ws[0] + ws[1] + ws[2] + ws[3];
        float cnt = (float)(hi - lo);
        out[g] = tot / fmaxf(cnt, 1.0f) + bfc[0];
    }
}

// ---------------- launch ----------------
extern "C" void kernel_launch(void* const* d_in, const int* in_sizes, int n_in,
                              void* d_out, int out_size, void* d_ws, size_t ws_size,
                              hipStream_t stream) {
    const float* x    = (const float*)d_in[0];
    const int*   ei   = (const int*)d_in[1];     // [2, E] : row0 = src, row1 = dst
    const int*   batch= (const int*)d_in[2];
    const float* W1   = (const float*)d_in[3];
    const float* b1   = (const float*)d_in[4];
    const float* W2   = (const float*)d_in[5];
    const float* b2   = (const float*)d_in[6];
    const float* W3   = (const float*)d_in[7];
    const float* b3   = (const float*)d_in[8];
    const float* Wfc  = (const float*)d_in[9];
    const float* bfc  = (const float*)d_in[10];
    float* out = (float*)d_out;

    const int* src = ei;
    const int* dst = ei + N_EDGES;

    // carve workspace (256B-aligned)
    char* p = (char*)d_ws;
    auto carve = [&](size_t bytes) { void* r = (void*)p; p += (bytes + 255) & ~(size_t)255; return r; };
    int*    cur       = (int*)   carve(sizeof(int) * NBUCK);
    uint32* bbuf      = (uint32*)carve(sizeof(uint32) * (size_t)NBUCK * BCAP);            // 7.2 MB
    float*  dinv      = (float*) carve(sizeof(float) * N_NODES);
    int*    offsets   = (int*)   carve(sizeof(int) * (N_NODES + 1));
    int*    col       = (int*)   carve(sizeof(int) * N_EDGES);
    ushort* XW        = (ushort*)carve(sizeof(short) * (size_t)N_NODES * NFEAT);
    ushort* H         = (ushort*)carve(sizeof(short) * (size_t)N_NODES * NFEAT);
    ushort* WT        = (ushort*)carve(sizeof(short) * 3 * NFEAT * NFEAT);
    float*  nodeS     = (float*) carve(sizeof(float) * N_NODES);

    const int aggBlocks = (N_NODES + 15) / 16;   // 4 nodes/wave * 4 waves/block = 16 nodes/block

    k_castw<<<(3 * NFEAT * NFEAT + 255) / 256, 256, 0, stream>>>(W1, W2, W3, WT, cur);
    // phase 1: scatter || layer-1 GEMM (independent work co-scheduled)  -> XW = x @ W1
    k_phase1<<<SC_BLOCKS + GEMM_BLOCKS, 512, 0, stream>>>(src, dst, cur, bbuf, x, WT, XW, N_NODES);
    k_build<<<NBUCK, 256, 0, stream>>>(bbuf, cur, col, offsets, dinv);

    k_agg<<<aggBlocks, 256, 0, stream>>>((const uint32*)XW, col, offsets, dinv, b1, (uint32*)H);
    // layer 2
    k_gemm<<<GEMM_BLOCKS, 512, 0, stream>>>(H, WT + NFEAT * NFEAT, XW, N_NODES);
    k_agg<<<aggBlocks, 256, 0, stream>>>((const uint32*)XW, col, offsets, dinv, b2, (uint32*)H);
    // layer 3
    k_gemm<<<GEMM_BLOCKS, 512, 0, stream>>>(H, WT + 2 * NFEAT * NFEAT, XW, N_NODES);
    k_agg_fc<<<aggBlocks, 256, 0, stream>>>((const uint32*)XW, col, offsets, dinv, b3, Wfc, nodeS);

    k_pool<<<N_GRAPHS, 256, 0, stream>>>(nodeS, batch, bfc, out);
}

// Round 5
// 351.381 us; speedup vs baseline: 1.2797x; 1.0082x over previous
//
#include <hip/hip_runtime.h>

#define N_NODES   100000
#define N_EDGES   1600000
#define NFEAT     128
#define N_GRAPHS  1024

// ---- bucketed CSR build ----
#define BSHIFT  8
#define BNODES  256
#define NBUCK   391                  // ceil(100000 / 256)
#define BCAP    4608                 // mean 4096 + 8 sigma
#define SC_EDGES 4096
#define SC_EPT   8                   // edges per thread (4096/512)
#define SC_BLOCKS 391                // ceil(1.6M / 4096)
#define BD_EPT   18                  // ceil(BCAP/256)

#define WT_STRIDE 136
#define GEMM_BLOCKS 782              // ceil(100000/128)

typedef unsigned int uint32;
typedef unsigned short ushort;
typedef __attribute__((ext_vector_type(8))) short short8;   // 8 bf16 (4 VGPRs)
typedef __attribute__((ext_vector_type(4))) float f32x4;

// fp32 -> bf16 bits, round-to-nearest-even (finite inputs)
__device__ inline ushort f2b(float f) {
    uint32 x = __float_as_uint(f);
    uint32 r = x + 0x7fffu + ((x >> 16) & 1u);
    return (ushort)(r >> 16);
}
__device__ inline float blo(uint32 u) { return __uint_as_float(u << 16); }
__device__ inline float bhi(uint32 u) { return __uint_as_float(u & 0xffff0000u); }

__device__ inline short8 cvt8(const float* p) {
    float4 v0 = ((const float4*)p)[0];
    float4 v1 = ((const float4*)p)[1];
    short8 r;
    r[0] = (short)f2b(v0.x); r[1] = (short)f2b(v0.y);
    r[2] = (short)f2b(v0.z); r[3] = (short)f2b(v0.w);
    r[4] = (short)f2b(v1.x); r[5] = (short)f2b(v1.y);
    r[6] = (short)f2b(v1.z); r[7] = (short)f2b(v1.w);
    return r;
}

// ---------------- cast+transpose W -> WT bf16 [layer][n][k]; also zero cur ----------------
__global__ __launch_bounds__(256) void k_castw(const float* __restrict__ W1, const float* __restrict__ W2,
                                               const float* __restrict__ W3, ushort* __restrict__ WT,
                                               int* __restrict__ cur) {
    int i = blockIdx.x * blockDim.x + threadIdx.x;   // 3*16384
    if (i < NBUCK) cur[i] = 0;
    if (i >= 3 * NFEAT * NFEAT) return;
    int l = i >> 14;
    int j = i & 16383;
    int n = j >> 7;
    int k = j & 127;
    const float* W = (l == 0) ? W1 : (l == 1) ? W2 : W3;
    WT[i] = f2b(W[k * NFEAT + n]);   // WT[l][n*128+k] = W[k][n]
}

// ---------------- phase 1: scatter (blocks 0..390) || layer-1 GEMM (blocks 391..1172) ----------------
struct SMemScatter {
    int hist[NBUCK], lofs[NBUCK], gbase[NBUCK];
    int wsum[4];
    uint32 sortedP[SC_EDGES];   // 16 KB
    ushort sortedB[SC_EDGES];   //  8 KB
};

__global__ __launch_bounds__(512) void k_phase1(const int* __restrict__ src, const int* __restrict__ dst,
                                                int* __restrict__ cur, uint32* __restrict__ bbuf,
                                                const float* __restrict__ A, const ushort* __restrict__ WTl,
                                                ushort* __restrict__ C, int M) {
    __shared__ __align__(16) char smem[NFEAT * WT_STRIDE * 2];   // 34 KB >= sizeof(SMemScatter)
    int t = threadIdx.x;
    if (blockIdx.x < SC_BLOCKS) {
        // ================== scatter: single-pass ticketed counting sort ==================
        SMemScatter& S = *(SMemScatter*)smem;
        int e0 = blockIdx.x * SC_EDGES;
        int total = N_EDGES - e0; if (total > SC_EDGES) total = SC_EDGES; if (total < 0) total = 0;
        for (int i = t; i < NBUCK; i += 512) S.hist[i] = 0;
        __syncthreads();
        uint32 val[SC_EPT];
        int    meta[SC_EPT];    // (bucket << 13) | ticket
        #pragma unroll
        for (int k = 0; k < SC_EPT; ++k) {
            int i = t + k * 512;
            meta[k] = -1;
            if (i < total) {
                int s = src[e0 + i], d = dst[e0 + i];
                int b = d >> BSHIFT;
                int tk = atomicAdd(&S.hist[b], 1);
                val[k] = ((uint32)(d & (BNODES - 1)) << 17) | (uint32)s;
                meta[k] = (b << 13) | tk;
            }
        }
        __syncthreads();
        // scan of 391 bins on first 256 threads (2/thread) + per-bin global reservation
        int inc = 0, ts = 0, h0 = 0;
        if (t < 256) {
            int b0 = 2 * t, b1 = 2 * t + 1;
            h0 = (b0 < NBUCK) ? S.hist[b0] : 0;
            int h1 = (b1 < NBUCK) ? S.hist[b1] : 0;
            ts = h0 + h1;
            int lane = t & 63;
            inc = ts;
            #pragma unroll
            for (int d = 1; d < 64; d <<= 1) {
                int u = __shfl_up(inc, d, 64);
                if (lane >= d) inc += u;
            }
            if (lane == 63) S.wsum[t >> 6] = inc;
        }
        __syncthreads();
        if (t < 256) {
            int w = t >> 6;
            int wpre = 0;
            for (int i = 0; i < w; ++i) wpre += S.wsum[i];
            int run = wpre + inc - ts;
            int b0 = 2 * t, b1 = 2 * t + 1;
            int h1 = ts - h0;
            if (b0 < NBUCK) {
                S.lofs[b0] = run;
                if (h0) S.gbase[b0] = atomicAdd(&cur[b0], h0);
            }
            if (b1 < NBUCK) {
                S.lofs[b1] = run + h0;
                if (h1) S.gbase[b1] = atomicAdd(&cur[b1], h1);
            }
        }
        __syncthreads();
        #pragma unroll
        for (int k = 0; k < SC_EPT; ++k) {
            if (meta[k] >= 0) {
                int b = meta[k] >> 13;
                int p = S.lofs[b] + (meta[k] & 0x1FFF);
                S.sortedP[p] = val[k];
                S.sortedB[p] = (ushort)b;
            }
        }
        __syncthreads();
        for (int i = t; i < total; i += 512) {
            int b = S.sortedB[i];
            int addr = S.gbase[b] + (i - S.lofs[b]);
            if (addr < BCAP)
                bbuf[(size_t)b * BCAP + addr] = S.sortedP[i];
        }
    } else {
        // ================== layer-1 GEMM (fp32 A, cast fused) ==================
        ushort* sWT = (ushort*)smem;
        int gb = blockIdx.x - SC_BLOCKS;
        for (int i = t; i < NFEAT * 16; i += 512) {
            int n = i >> 4, c = i & 15;
            *(float4*)(sWT + n * WT_STRIDE + c * 8) = ((const float4*)WTl)[i];
        }
        int wave = t >> 6, lane = t & 63;
        int m0 = gb * 128 + wave * 16;
        int mRow = m0 + (lane & 15);
        if (mRow >= M) mRow = M - 1;
        int kg = lane >> 4;
        const float* Ap = A + (size_t)mRow * NFEAT + kg * 8;
        short8 a0 = cvt8(Ap);
        short8 a1 = cvt8(Ap + 32);
        short8 a2 = cvt8(Ap + 64);
        short8 a3 = cvt8(Ap + 96);
        __syncthreads();

        f32x4 acc[8];
        #pragma unroll
        for (int nt = 0; nt < 8; ++nt) acc[nt] = (f32x4){0.f, 0.f, 0.f, 0.f};
        #pragma unroll
        for (int nt = 0; nt < 8; ++nt) {
            int n = nt * 16 + (lane & 15);
            const short8* Bp = (const short8*)(sWT + n * WT_STRIDE + kg * 8);
            short8 b0 = Bp[0];
            short8 b1 = Bp[4];
            short8 b2 = Bp[8];
            short8 b3 = Bp[12];
            acc[nt] = __builtin_amdgcn_mfma_f32_16x16x32_bf16(a0, b0, acc[nt], 0, 0, 0);
            acc[nt] = __builtin_amdgcn_mfma_f32_16x16x32_bf16(a1, b1, acc[nt], 0, 0, 0);
            acc[nt] = __builtin_amdgcn_mfma_f32_16x16x32_bf16(a2, b2, acc[nt], 0, 0, 0);
            acc[nt] = __builtin_amdgcn_mfma_f32_16x16x32_bf16(a3, b3, acc[nt], 0, 0, 0);
        }
        __syncthreads();
        {
            int colBase = lane & 15;
            #pragma unroll
            for (int r = 0; r < 4; ++r) {
                int lr = wave * 16 + kg * 4 + r;
                #pragma unroll
                for (int nt = 0; nt < 8; ++nt)
                    sWT[lr * NFEAT + nt * 16 + colBase] = f2b(acc[nt][r]);
            }
        }
        __syncthreads();
        {
            int rowBase = gb * 128;
            const float4* sC4 = (const float4*)sWT;
            for (int i = t; i < 2048; i += 512) {
                int row = i >> 4;
                int gr = rowBase + row;
                if (gr < M) ((float4*)(C + (size_t)gr * NFEAT))[i & 15] = sC4[i];
            }
        }
    }
}

// ---------------- per-bucket ticketed counting sort -> CSR col + offsets + dinv ----------------
__global__ __launch_bounds__(256) void k_build(const uint32* __restrict__ bbuf, const int* __restrict__ cur,
                                               int* __restrict__ col, int* __restrict__ offsets,
                                               float* __restrict__ dinv) {
    int b = blockIdx.x;
    __shared__ int hist[BNODES], excl[BNODES];
    __shared__ int wsum[4], wtot[4];
    __shared__ int sorted[BCAP];              // 18 KB
    __shared__ int sBase, sTotal;
    int t = threadIdx.x;
    {
        int pre = 0, tot = 0;
        #pragma unroll
        for (int q = 0; q < 2; ++q) {
            int i = 2 * t + q;
            if (i < NBUCK) {
                int v = cur[i]; if (v > BCAP) v = BCAP;
                tot += v;
                if (i < b) pre += v;
            }
        }
        int lane = t & 63, w = t >> 6;
        #pragma unroll
        for (int d = 32; d > 0; d >>= 1) { pre += __shfl_down(pre, d, 64); tot += __shfl_down(tot, d, 64); }
        if (lane == 0) { wsum[w] = pre; wtot[w] = tot; }
        __syncthreads();
        if (t == 0) {
            sBase = wsum[0] + wsum[1] + wsum[2] + wsum[3];
            sTotal = wtot[0] + wtot[1] + wtot[2] + wtot[3];
        }
        hist[t] = 0;
    }
    __syncthreads();
    int base = sBase;
    if (b == NBUCK - 1 && t == 0) offsets[N_NODES] = sTotal;
    int cnt = cur[b]; if (cnt > BCAP) cnt = BCAP;
    const uint32* reg = bbuf + (size_t)b * BCAP;

    uint32 val[BD_EPT];
    int    meta[BD_EPT];   // (node << 16) | ticket
    #pragma unroll
    for (int k = 0; k < BD_EPT; ++k) {
        int i = t + k * 256;
        meta[k] = -1;
        if (i < cnt) {
            uint32 p = reg[i];
            int node = p >> 17;
            int tk = atomicAdd(&hist[node], 1);
            val[k] = p & 0x1FFFF;
            meta[k] = (node << 16) | tk;
        }
    }
    __syncthreads();
    {
        int c = hist[t];
        int lane = t & 63, w = t >> 6;
        int inc = c;
        #pragma unroll
        for (int d = 1; d < 64; d <<= 1) {
            int u = __shfl_up(inc, d, 64);
            if (lane >= d) inc += u;
        }
        if (lane == 63) wsum[w] = inc;
        __syncthreads();
        int wpre = 0;
        for (int i = 0; i < w; ++i) wpre += wsum[i];
        int e = wpre + inc - c;
        excl[t] = e;
        int node = (b << BSHIFT) + t;
        if (node < N_NODES) {
            offsets[node] = base + e;
            dinv[node] = rsqrtf((float)(c + 1));
        }
    }
    __syncthreads();
    #pragma unroll
    for (int k = 0; k < BD_EPT; ++k) {
        if (meta[k] >= 0) {
            int node = meta[k] >> 16;
            sorted[excl[node] + (meta[k] & 0xFFFF)] = (int)val[k];
        }
    }
    __syncthreads();
    for (int i = t; i < cnt; i += 256) col[base + i] = sorted[i];
}

// ---------------- aggregation core: 4 nodes per wave, 8-wide gather pipeline ----------------
// Each 16-lane group owns one node. Group-local accumulators, fully lane-active stores.
// 8 uint4 gathers in flight; next chunk's col/dinv prefetched under current chunk's FMAs;
// no serial tail (overflow slots carry wm=0/cm=0: base+slot >= maxd >= deg for slot >= lim).
#define AGG_GROUP4 \
    int half = lane >> 4; \
    int fl = lane & 15; \
    float dn = dinv[n]; \
    int e0 = off[n], e1 = off[n + 1]; \
    int deg = e1 - e0; \
    int maxd = deg; \
    { int u16 = __shfl_xor(maxd, 16, 64); if (u16 > maxd) maxd = u16; \
      int u32 = __shfl_xor(maxd, 32, 64); if (u32 > maxd) maxd = u32; } \
    const uint4* XW4 = (const uint4*)XWu; \
    uint4 sv = XW4[(size_t)n * 16 + fl]; \
    float ws = dn * dn; \
    float a0 = ws * blo(sv.x), a1 = ws * bhi(sv.x); \
    float a2 = ws * blo(sv.y), a3 = ws * bhi(sv.y); \
    float a4 = ws * blo(sv.z), a5 = ws * bhi(sv.z); \
    float a6 = ws * blo(sv.w), a7 = ws * bhi(sv.w); \
    int cm = 0; float wm = 0.f; \
    if (fl < deg) { cm = col[e0 + fl]; wm = dn * dinv[cm]; } \
    for (int base = 0; base < maxd; base += 16) { \
        int nb = base + 16; \
        int cmn = 0; float wmn = 0.f; \
        if (nb + fl < deg) { cmn = col[e0 + nb + fl]; wmn = dn * dinv[cmn]; } \
        int lim = maxd - base; if (lim > 16) lim = 16; \
        for (int j = 0; j < lim; j += 8) { \
            uint4 u[8]; float w[8]; \
            _Pragma("unroll") \
            for (int p = 0; p < 8; ++p) { \
                int sl = (half << 4) + j + p; \
                int cc = __shfl(cm, sl, 64); \
                w[p] = __shfl(wm, sl, 64); \
                u[p] = XW4[(size_t)cc * 16 + fl]; \
            } \
            _Pragma("unroll") \
            for (int p = 0; p < 8; ++p) { \
                a0 = fmaf(w[p], blo(u[p].x), a0); a1 = fmaf(w[p], bhi(u[p].x), a1); \
                a2 = fmaf(w[p], blo(u[p].y), a2); a3 = fmaf(w[p], bhi(u[p].y), a3); \
                a4 = fmaf(w[p], blo(u[p].z), a4); a5 = fmaf(w[p], bhi(u[p].z), a5); \
                a6 = fmaf(w[p], blo(u[p].w), a6); a7 = fmaf(w[p], bhi(u[p].w), a7); \
            } \
        } \
        cm = cmn; wm = wmn; \
    }

// ---------------- fused: agg(+bias,relu) 16 nodes/block -> 4.3KB LDS A-tile -> MFMA @ W ----------------
// Same agg structure & grid as k_agg (6250 blocks, 4 waves, 4 nodes/wave); the dense GEMM that
// used to be a separate kernel becomes a per-block epilogue: each wave computes 2 of the 8
// column-tiles of C[16,128] = A[16,128] @ W. Kills the H write+read (51 MB/layer) + 1 launch.
// B-fragments read from global WT (32 KB, L2-hot) — identical pattern verified in R0 phase B.
__global__ __launch_bounds__(256) void k_agg_gemm(const uint32* __restrict__ XWu,
                                                  const int* __restrict__ col,
                                                  const int* __restrict__ off,
                                                  const float* __restrict__ dinv,
                                                  const float* __restrict__ bias,
                                                  const ushort* __restrict__ WTl,
                                                  ushort* __restrict__ C) {
    __shared__ __align__(16) ushort sA[16 * WT_STRIDE];   // 4.25 KB (A-tile, reused for C staging)
    int t = threadIdx.x;
    int lane = t & 63;
    int lw = t >> 6;                                      // wave 0..3
    int n = (blockIdx.x << 4) + (lw << 2) + (lane >> 4);  // N_NODES = 6250*16 exactly, no tail
    AGG_GROUP4
    // bias + relu + pack to bf16, stage row into LDS
    {
        float4 bb0 = ((const float4*)bias)[2 * fl];
        float4 bb1 = ((const float4*)bias)[2 * fl + 1];
        float r0 = fmaxf(a0 + bb0.x, 0.f), r1 = fmaxf(a1 + bb0.y, 0.f);
        float r2 = fmaxf(a2 + bb0.z, 0.f), r3 = fmaxf(a3 + bb0.w, 0.f);
        float r4 = fmaxf(a4 + bb1.x, 0.f), r5 = fmaxf(a5 + bb1.y, 0.f);
        float r6 = fmaxf(a6 + bb1.z, 0.f), r7 = fmaxf(a7 + bb1.w, 0.f);
        uint4 o;
        o.x = (uint32)f2b(r0) | ((uint32)f2b(r1) << 16);
        o.y = (uint32)f2b(r2) | ((uint32)f2b(r3) << 16);
        o.z = (uint32)f2b(r4) | ((uint32)f2b(r5) << 16);
        o.w = (uint32)f2b(r6) | ((uint32)f2b(r7) << 16);
        int lrow = (lw << 2) + half;                      // local node 0..15
        *(uint4*)(sA + lrow * WT_STRIDE + fl * 8) = o;
    }
    __syncthreads();
    // GEMM epilogue: wave lw computes column-tiles nt = 2lw, 2lw+1 of C[16,128]
    {
        const short8* Ap = (const short8*)(sA + fl * WT_STRIDE + half * 8);
        short8 af0 = Ap[0];
        short8 af1 = Ap[4];
        short8 af2 = Ap[8];
        short8 af3 = Ap[12];
        f32x4 acc[2];
        acc[0] = (f32x4){0.f, 0.f, 0.f, 0.f};
        acc[1] = (f32x4){0.f, 0.f, 0.f, 0.f};
        #pragma unroll
        for (int q = 0; q < 2; ++q) {
            int nt = lw * 2 + q;
            const short8* Bp = (const short8*)(WTl + (nt * 16 + fl) * NFEAT + half * 8);
            short8 b0 = Bp[0];
            short8 b1 = Bp[4];
            short8 b2 = Bp[8];
            short8 b3 = Bp[12];
            acc[q] = __builtin_amdgcn_mfma_f32_16x16x32_bf16(af0, b0, acc[q], 0, 0, 0);
            acc[q] = __builtin_amdgcn_mfma_f32_16x16x32_bf16(af1, b1, acc[q], 0, 0, 0);
            acc[q] = __builtin_amdgcn_mfma_f32_16x16x32_bf16(af2, b2, acc[q], 0, 0, 0);
            acc[q] = __builtin_amdgcn_mfma_f32_16x16x32_bf16(af3, b3, acc[q], 0, 0, 0);
        }
        __syncthreads();
        // C/D layout: col = lane&15 (fl), row = (lane>>4)*4 + r (half*4+r)
        #pragma unroll
        for (int q = 0; q < 2; ++q) {
            int nt = lw * 2 + q;
            #pragma unroll
            for (int r = 0; r < 4; ++r)
                sA[(half * 4 + r) * NFEAT + nt * 16 + fl] = f2b(acc[q][r]);
        }
    }
    __syncthreads();
    {
        int row = t >> 4;                                 // 0..15
        float4 v = ((const float4*)sA)[t];                // 256 float4 = 16 rows x 128 ushort
        ((float4*)(C + (size_t)((blockIdx.x << 4) + row) * NFEAT))[t & 15] = v;
    }
}

__global__ __launch_bounds__(256) void k_agg_fc(const uint32* __restrict__ XWu, const int* __restrict__ col,
                                                const int* __restrict__ off, const float* __restrict__ dinv,
                                                const float* __restrict__ bias, const float* __restrict__ Wfc,
                                                float* __restrict__ nodeS) {
    int wid = (blockIdx.x * blockDim.x + threadIdx.x) >> 6;
    int lane = threadIdx.x & 63;
    int n = (wid << 2) + (lane >> 4);
    if (n >= N_NODES) return;
    AGG_GROUP4
    float4 bb0 = ((const float4*)bias)[2 * fl];
    float4 bb1 = ((const float4*)bias)[2 * fl + 1];
    float4 wf0 = ((const float4*)Wfc)[2 * fl];
    float4 wf1 = ((const float4*)Wfc)[2 * fl + 1];
    float s = fmaxf(a0 + bb0.x, 0.f) * wf0.x + fmaxf(a1 + bb0.y, 0.f) * wf0.y
            + fmaxf(a2 + bb0.z, 0.f) * wf0.z + fmaxf(a3 + bb0.w, 0.f) * wf0.w
            + fmaxf(a4 + bb1.x, 0.f) * wf1.x + fmaxf(a5 + bb1.y, 0.f) * wf1.y
            + fmaxf(a6 + bb1.z, 0.f) * wf1.z + fmaxf(a7 + bb1.w, 0.f) * wf1.w;
    // reduce within the 16-lane group (xor distances 8/4/2/1 stay inside the group)
    s += __shfl_xor(s, 8, 64);
    s += __shfl_xor(s, 4, 64);
    s += __shfl_xor(s, 2, 64);
    s += __shfl_xor(s, 1, 64);
    if (fl == 0) nodeS[n] = s;
}

// ---------------- segment mean over sorted batch + bias (one block per graph) ----------------
__device__ inline int lower_bound_dev(const int* a, int n, int key) {
    int lo = 0, hi = n;
    while (lo < hi) {
        int mid = (lo + hi) >> 1;
        if (a[mid] < key) lo = mid + 1; else hi = mid;
    }
    return lo;
}

__global__ __launch_bounds__(256) void k_pool(const float* __restrict__ nodeS, const int* __restrict__ batch,
                                              const float* __restrict__ bfc, float* __restrict__ out) {
    int g = blockIdx.x;
    int t = threadIdx.x;
    int lo = lower_bound_dev(batch, N_NODES, g);
    int hi = lower_bound_dev(batch, N_NODES, g + 1);
    float s = 0.f;
    for (int i = lo + t; i < hi; i += 256) s += nodeS[i];
    for (int d = 32; d > 0; d >>= 1) s += __shfl_down(s, d, 64);
    __shared__ float ws[4];
    int lane = t & 63, w = t >> 6;
    if (lane == 0) ws[w] = s;
    __syncthreads();
    if (t == 0) {
        float tot = ws[0] + ws[1] + ws[2] + ws[3];
        float cnt = (float)(hi - lo);
        out[g] = tot / fmaxf(cnt, 1.0f) + bfc[0];
    }
}

// ---------------- launch ----------------
extern "C" void kernel_launch(void* const* d_in, const int* in_sizes, int n_in,
                              void* d_out, int out_size, void* d_ws, size_t ws_size,
                              hipStream_t stream) {
    const float* x    = (const float*)d_in[0];
    const int*   ei   = (const int*)d_in[1];     // [2, E] : row0 = src, row1 = dst
    const int*   batch= (const int*)d_in[2];
    const float* W1   = (const float*)d_in[3];
    const float* b1   = (const float*)d_in[4];
    const float* W2   = (const float*)d_in[5];
    const float* b2   = (const float*)d_in[6];
    const float* W3   = (const float*)d_in[7];
    const float* b3   = (const float*)d_in[8];
    const float* Wfc  = (const float*)d_in[9];
    const float* bfc  = (const float*)d_in[10];
    float* out = (float*)d_out;

    const int* src = ei;
    const int* dst = ei + N_EDGES;

    // carve workspace (256B-aligned)
    char* p = (char*)d_ws;
    auto carve = [&](size_t bytes) { void* r = (void*)p; p += (bytes + 255) & ~(size_t)255; return r; };
    int*    cur       = (int*)   carve(sizeof(int) * NBUCK);
    uint32* bbuf      = (uint32*)carve(sizeof(uint32) * (size_t)NBUCK * BCAP);            // 7.2 MB
    float*  dinv      = (float*) carve(sizeof(float) * N_NODES);
    int*    offsets   = (int*)   carve(sizeof(int) * (N_NODES + 1));
    int*    col       = (int*)   carve(sizeof(int) * N_EDGES);
    ushort* XW        = (ushort*)carve(sizeof(short) * (size_t)N_NODES * NFEAT);
    ushort* XW2       = (ushort*)carve(sizeof(short) * (size_t)N_NODES * NFEAT);          // ping-pong
    ushort* WT        = (ushort*)carve(sizeof(short) * 3 * NFEAT * NFEAT);
    float*  nodeS     = (float*) carve(sizeof(float) * N_NODES);

    const int aggBlocks = N_NODES / 16;   // 6250 exactly (100000 = 6250*16)

    k_castw<<<(3 * NFEAT * NFEAT + 255) / 256, 256, 0, stream>>>(W1, W2, W3, WT, cur);
    // phase 1: scatter || layer-1 GEMM (independent work co-scheduled)  -> XW = x @ W1
    k_phase1<<<SC_BLOCKS + GEMM_BLOCKS, 512, 0, stream>>>(src, dst, cur, bbuf, x, WT, XW, N_NODES);
    k_build<<<NBUCK, 256, 0, stream>>>(bbuf, cur, col, offsets, dinv);

    // fused layer-1 agg + layer-2 GEMM:  XW2 = relu(A·XW + b1) @ W2
    k_agg_gemm<<<aggBlocks, 256, 0, stream>>>((const uint32*)XW, col, offsets, dinv, b1,
                                              WT + NFEAT * NFEAT, XW2);
    // fused layer-2 agg + layer-3 GEMM:  XW = relu(A·XW2 + b2) @ W3
    k_agg_gemm<<<aggBlocks, 256, 0, stream>>>((const uint32*)XW2, col, offsets, dinv, b2,
                                              WT + 2 * NFEAT * NFEAT, XW);
    // layer-3 agg + FC
    k_agg_fc<<<aggBlocks, 256, 0, stream>>>((const uint32*)XW, col, offsets, dinv, b3, Wfc, nodeS);

    k_pool<<<N_GRAPHS, 256, 0, stream>>>(nodeS, batch, bfc, out);
}